// Round 14
// baseline (1194.624 us; speedup 1.0000x reference)
//
#include <hip/hip_runtime.h>
#include <hip/hip_bf16.h>

#define H 128
#define HH 16384
#define LNUM 4
#define NN 4096
#define SS 8192
#define SKK 262144
#define EI 1048576
#define EG 65536
#define NGRAPH 64

typedef unsigned short u16;
typedef unsigned int u32;
typedef __attribute__((ext_vector_type(8))) short s16x8;
typedef __attribute__((ext_vector_type(4))) float f32x4;

__device__ __forceinline__ float b2f(u32 u){ return __uint_as_float(u<<16); }
__device__ __forceinline__ u16 f2b(float f){
  union { __hip_bfloat16 b; u16 u; } x;
  x.b=__float2bfloat16(f);
  return x.u;
}
__device__ __forceinline__ void unp8(uint4 v, float* f){
  f[0]=b2f(v.x&0xFFFF); f[1]=b2f(v.x>>16);
  f[2]=b2f(v.y&0xFFFF); f[3]=b2f(v.y>>16);
  f[4]=b2f(v.z&0xFFFF); f[5]=b2f(v.z>>16);
  f[6]=b2f(v.w&0xFFFF); f[7]=b2f(v.w>>16);
}
__device__ __forceinline__ void unp4(uint2 v, float* f){
  f[0]=b2f(v.x&0xFFFF); f[1]=b2f(v.x>>16);
  f[2]=b2f(v.y&0xFFFF); f[3]=b2f(v.y>>16);
}
__device__ __forceinline__ uint4 pk8(const float* f){
  uint4 r;
  r.x=(u32)f2b(f[0])|((u32)f2b(f[1])<<16);
  r.y=(u32)f2b(f[2])|((u32)f2b(f[3])<<16);
  r.z=(u32)f2b(f[4])|((u32)f2b(f[5])<<16);
  r.w=(u32)f2b(f[6])|((u32)f2b(f[7])<<16);
  return r;
}
__device__ __forceinline__ uint2 pk4(const float* f){
  uint2 r;
  r.x=(u32)f2b(f[0])|((u32)f2b(f[1])<<16);
  r.y=(u32)f2b(f[2])|((u32)f2b(f[3])<<16);
  return r;
}
// tanh-form gelu
__device__ __forceinline__ float gelu_f(float x){
  float u=x*(0.7978845608f+0.0356774081f*x*x);
  float ex=__expf(fminf(2.f*u,80.f));
  return x*(ex/(ex+1.f));
}

struct CvtArgs {
  const void* p[26];
  int start[27];
};
struct TransArgs { int src[28]; };

// ---- dtype sniff
__global__ void k_sniff(const u16* __restrict__ a, int* __restrict__ flag){
  __shared__ int cnt;
  if(threadIdx.x==0) cnt=0;
  __syncthreads();
  int big=0;
  for(int i=threadIdx.x;i<2048;i+=256){
    int e=(a[i]>>7)&0xFF;
    if(e>=127) big++;
  }
  atomicAdd(&cnt,big);
  __syncthreads();
  if(threadIdx.x==0) *flag=(cnt<16)?1:0;
}

__global__ void k_convert(CvtArgs args, const int* __restrict__ flag, float* __restrict__ dst){
  int fl=*flag;
  int total=args.start[26];
  for(int i=blockIdx.x*blockDim.x+threadIdx.x;i<total;i+=gridDim.x*blockDim.x){
    int a=0;
    while(args.start[a+1]<=i) a++;
    int j=i-args.start[a];
    float v;
    if(fl) v=b2f(((const u16*)args.p[a])[j]);
    else   v=((const float*)args.p[a])[j];
    dst[i]=v;
  }
}

// ---- static weights: f32 [K][N] -> bf16 fragment-major packed
__global__ __launch_bounds__(256) void k_trans(const float* __restrict__ par, TransArgs ta, u16* __restrict__ wt){
  const float* s=par+ta.src[blockIdx.x];
  u16* d=wt+(size_t)blockIdx.x*HH;
  for(int i=threadIdx.x;i<HH;i+=256){
    int j=i&7, lane=(i>>3)&63, fc=i>>9;
    int n=fc>>2, kc=fc&3, lr=lane&15, lk=lane>>4;
    int outc=n*16+lr, k=kc*32+lk*8+j;
    d[i]=f2b(s[(size_t)k*H+outc]);
  }
}

// ---- bond emb f32 -> bf16
__global__ void k_cvtbond(const float* __restrict__ b, u16* __restrict__ bb){
  int i=blockIdx.x*blockDim.x+threadIdx.x;
  if(i<16*H) bb[i]=f2b(b[i]);
}

// ---- fold local-BN affine into cw1_top, packed output
__global__ __launch_bounds__(128) void k_prepw3(const float* __restrict__ w, const float* __restrict__ cb1,
                        const float* __restrict__ stl, const float* __restrict__ gl, const float* __restrict__ bl,
                        u16* __restrict__ wt3p, float* __restrict__ bias3){
  __shared__ float red[128];
  int c=blockIdx.x, k=threadIdx.x;
  float mu=stl[k]*(1.f/262144.f);
  float var=stl[128+k]*(1.f/262144.f)-mu*mu;
  float s=gl[k]*rsqrtf(var+1e-5f);
  float tt=bl[k]-mu*s;
  float wv=w[(size_t)k*H+c];
  int idx=(((c>>4)*4+(k>>5))*64+((k>>3)&3)*16+(c&15))*8+(k&7);
  wt3p[idx]=f2b(s*wv);
  red[k]=tt*wv;
  __syncthreads();
  for(int d=64;d>0;d>>=1){ if(k<d) red[k]+=red[k+d]; __syncthreads(); }
  if(k==0) bias3[c]=cb1[c]+red[0];
}

// ---- edge bucketing
__global__ void k_hist(const int* __restrict__ idx, int n, int shift, int* __restrict__ cnt){
  for(int i=blockIdx.x*blockDim.x+threadIdx.x;i<n;i+=gridDim.x*blockDim.x)
    atomicAdd(&cnt[idx[i]>>shift],1);
}

__global__ void k_scan(const int* __restrict__ cnt, int* __restrict__ off, int nbins){
  __shared__ int ts[1024];
  int t=threadIdx.x;
  int per=nbins>>10;
  int base=t*per;
  int s=0;
  for(int j=0;j<per;j++) s+=cnt[base+j];
  ts[t]=s;
  __syncthreads();
  for(int d=1;d<1024;d<<=1){
    int v=(t>=d)?ts[t-d]:0;
    __syncthreads();
    ts[t]+=v;
    __syncthreads();
  }
  int ex=(t==0)?0:ts[t-1];
  for(int j=0;j<per;j++){ off[base+j]=ex; ex+=cnt[base+j]; }
}

__global__ void k_scatter_i(const int* __restrict__ ei, const int* __restrict__ ea,
                            const int* __restrict__ off, int* __restrict__ cur, int* __restrict__ pack){
  for(int i=blockIdx.x*blockDim.x+threadIdx.x;i<EI;i+=gridDim.x*blockDim.x){
    int s=ei[i], d=ei[EI+i];
    int sub=d>>5;
    int pos=off[sub]+atomicAdd(&cur[sub],1);
    pack[pos]=((s&31)<<9)|((d&31)<<4)|(ea[i]&15);
  }
}

// ---- sort each subgraph's edges by dst-lane; persist per-dst segment starts
__global__ __launch_bounds__(128) void k_sortsub(const int* __restrict__ eoff, const int* __restrict__ ecnt,
                                                 int* __restrict__ epack, int* __restrict__ dstoff){
  __shared__ int ein[512];
  __shared__ int eout[512];
  __shared__ int bcnt[32];
  __shared__ int bpos[32];
  int sub=blockIdx.x, t=threadIdx.x;
  int o=eoff[sub];
  int n=ecnt[sub]; if(n>512) n=512;
  for(int i=t;i<n;i+=128) ein[i]=epack[o+i];
  if(t<32) bcnt[t]=0;
  __syncthreads();
  for(int i=t;i<n;i+=128) atomicAdd(&bcnt[(ein[i]>>4)&31],1);
  __syncthreads();
  if(t==0){
    int s=0;
    for(int b=0;b<32;b++){ bpos[b]=s; s+=bcnt[b]; }
  }
  __syncthreads();
  if(t<32) dstoff[sub*32+t]=bpos[t];
  __syncthreads();
  for(int i=t;i<n;i+=128){
    int p=ein[i];
    int pos=atomicAdd(&bpos[(p>>4)&31],1);
    eout[pos]=p;
  }
  __syncthreads();
  for(int i=t;i<n;i+=128) epack[o+i]=eout[i];
}

__global__ void k_scatter_g(const int* __restrict__ ei, const int* __restrict__ ea,
                            const int* __restrict__ off, int* __restrict__ cur, int* __restrict__ pack){
  for(int i=blockIdx.x*blockDim.x+threadIdx.x;i<EG;i+=gridDim.x*blockDim.x){
    int s=ei[i], d=ei[EG+i];
    int pos=off[d]+atomicAdd(&cur[d],1);
    pack[pos]=(s<<4)|(ea[i]&15);
  }
}

// ---- rf = relu(rwse @ rwse_w + rwse_b)
__global__ __launch_bounds__(128) void k_rwse(const float* __restrict__ rwse, const float* __restrict__ w,
                      const float* __restrict__ b, float* __restrict__ rf){
  __shared__ float ws[16*128];
  __shared__ float rv[16];
  int n=blockIdx.x, c=threadIdx.x;
  for(int i=c;i<2048;i+=128) ws[i]=w[i];
  if(c<16) rv[c]=rwse[n*16+c];
  __syncthreads();
  float acc=b[c];
  for(int j=0;j<16;j++) acc=fmaf(rv[j],ws[j*128+c],acc);
  rf[(size_t)n*H+c]=fmaxf(acc,0.f);
}

// ==== FUSED mega-kernel. MODE 1: prev-layer tail first. MODE 2: build h0 in-block.
template<int MODE>
__global__ __launch_bounds__(256,4) void k_fused1(
    const u16* __restrict__ h, const u16* __restrict__ beb,
    const int* __restrict__ eoff, const int* __restrict__ ecnt, const int* __restrict__ epack,
    const int* __restrict__ dstoff,
    const float* __restrict__ epsp, int layer,
    const u16* __restrict__ W1p, const float* __restrict__ b1,
    const u16* __restrict__ W2p, const float* __restrict__ b2,
    u16* __restrict__ Xg, float* __restrict__ stats,
    const u16* __restrict__ W3p, const float* __restrict__ bias3,
    const u16* __restrict__ bbv,
    const u16* __restrict__ Wc2p, const float* __restrict__ cb2,
    const float* __restrict__ lng, const float* __restrict__ lnb,
    const int* __restrict__ validv, u16* __restrict__ hio,
    const float* __restrict__ atomp, const float* __restrict__ rfp,
    const int* __restrict__ xids, const int* __restrict__ nids,
    u16* __restrict__ hnOut)
{
  __shared__ u16 hs[64*128];
  __shared__ u16 agx[64*128];
  __shared__ u16 bes[16*128];
  __shared__ u16 epku[2][512];
  __shared__ int doff[2][32];
  float* sst=(float*)&epku[0][0];

  int t=threadIdx.x;
  int grp=t>>7, c=t&127;
  size_t hbase=(size_t)blockIdx.x*64*H;
  int wave=t>>6, lane=t&63, lr=lane&15, lk=lane>>4;
  int rl=wave*16+lr;
  u32 rsw=((u32)(rl&7))<<4;
  int row0=blockIdx.x*64;

  {
    u32 row=(u32)(t>>4), colb=(u32)((t&15)*16);
    *(uint4*)((char*)bes+row*256+(colb^((row&7)<<4)))=((const uint4*)beb)[t];
  }
  int sub=blockIdx.x*2+grp;
  int n=min(ecnt[sub],512);
  int o=eoff[sub];
  if(c<32) doff[grp][c]=dstoff[sub*32+c];
  for(int i=c;i<n;i+=128) epku[grp][i]=(u16)epack[o+i];

  if(MODE==1){
    f32x4 a1t[8];
    #pragma unroll
    for(int n8=0;n8<8;n8++) a1t[n8]=(f32x4){0.f,0.f,0.f,0.f};
    const s16x8* B0=(const s16x8*)(Xg+(size_t)(row0+rl)*H);
    #pragma unroll
    for(int kc=0;kc<4;kc++){
      s16x8 bf=B0[kc*4+lk];
      #pragma unroll
      for(int n8=0;n8<8;n8++){
        s16x8 af=*(const s16x8*)(W3p+((n8*4+kc)<<9)+lane*8);
        a1t[n8]=__builtin_amdgcn_mfma_f32_16x16x32_bf16(af,bf,a1t[n8],0,0,0);
      }
    }
    #pragma unroll
    for(int n8=0;n8<8;n8++){
      int c0=n8*16+lk*4;
      float4 b4=*(const float4*)(bias3+c0);
      float rb[4];
      unp4(*(const uint2*)(bbv+(size_t)blockIdx.x*H+c0),rb);
      float vb[4]={b4.x,b4.y,b4.z,b4.w};
      float v[4];
      #pragma unroll
      for(int j=0;j<4;j++){
        v[j]=gelu_f(a1t[n8][j]+vb[j]+rb[j]);
      }
      *(uint2*)((char*)agx+(u32)rl*256+(((u32)(2*c0))^rsw))=pk4(v);
    }
    f32x4 a2t[8];
    #pragma unroll
    for(int n8=0;n8<8;n8++) a2t[n8]=(f32x4){0.f,0.f,0.f,0.f};
    #pragma unroll
    for(int kc=0;kc<4;kc++){
      u32 cb=(u32)((kc*32+lk*8)*2);
      s16x8 bf=*(const s16x8*)((char*)agx+(u32)rl*256+(cb^rsw));
      #pragma unroll
      for(int n8=0;n8<8;n8++){
        s16x8 af=*(const s16x8*)(Wc2p+((n8*4+kc)<<9)+lane*8);
        a2t[n8]=__builtin_amdgcn_mfma_f32_16x16x32_bf16(af,bf,a2t[n8],0,0,0);
      }
    }
    {
      float s=0.f,q=0.f;
      #pragma unroll
      for(int n8=0;n8<8;n8++){
        int c0=n8*16+lk*4;
        float4 b4=*(const float4*)(cb2+c0);
        float vb[4]={b4.x,b4.y,b4.z,b4.w};
        #pragma unroll
        for(int j=0;j<4;j++){
          float v=a2t[n8][j]+vb[j];
          a2t[n8][j]=v;
          s+=v; q+=v*v;
        }
      }
      s+=__shfl_xor(s,16); s+=__shfl_xor(s,32);
      q+=__shfl_xor(q,16); q+=__shfl_xor(q,32);
      float mu=s*(1.f/128.f);
      float rsig=rsqrtf(q*(1.f/128.f)-mu*mu+1e-5f);
      #pragma unroll
      for(int n8=0;n8<8;n8++){
        int c0=n8*16+lk*4;
        float4 g4=*(const float4*)(lng+c0);
        float4 e4=*(const float4*)(lnb+c0);
        float g[4]={g4.x,g4.y,g4.z,g4.w}, e[4]={e4.x,e4.y,e4.z,e4.w};
        float ov[4];
        #pragma unroll
        for(int j=0;j<4;j++) ov[j]=(a2t[n8][j]-mu)*rsig*g[j]+e[j];
        *(uint2*)((char*)agx+(u32)rl*256+(((u32)(2*c0))^rsw))=pk4(ov);
      }
    }
    __syncthreads();
    uint4* hp=(uint4*)(hio+hbase);
    #pragma unroll
    for(int p=0;p<4;p++){
      int i=t+p*256;
      u32 row=(u32)(i>>4), colb=(u32)((i&15)*16);
      int grow=row0+(int)row;
      uint4 v=*(const uint4*)((const char*)agx+row*256+(colb^((row&7)<<4)));
      uint4 r=hp[i];
      float vv[8],rv[8],o8[8];
      unp8(v,vv); unp8(r,rv);
      float vm=validv[grow]?1.f:0.f;
      #pragma unroll
      for(int j=0;j<8;j++) o8[j]=(rv[j]+vv[j])*vm;
      uint4 pk=pk8(o8);
      hp[i]=pk;
      *(uint4*)((char*)hs+row*256+(colb^((row&7)<<4)))=pk;
    }
  } else {
    int r=t>>2, q=t&3;
    int grow=row0+r;
    float vm=validv[grow]?1.f:0.f;
    const float4* ap=(const float4*)(atomp+(size_t)xids[grow]*H)+q*8;
    const float4* bp=(const float4*)(rfp+(size_t)nids[grow]*H)+q*8;
    u32 rowsw=((u32)(r&7))<<4;
    uint4* hgp=(uint4*)(hio+hbase);
    #pragma unroll
    for(int k=0;k<4;k++){
      float4 a0=ap[k*2], a1=ap[k*2+1], b0=bp[k*2], b1=bp[k*2+1];
      float f[8]={(a0.x+b0.x)*vm,(a0.y+b0.y)*vm,(a0.z+b0.z)*vm,(a0.w+b0.w)*vm,
                  (a1.x+b1.x)*vm,(a1.y+b1.y)*vm,(a1.z+b1.z)*vm,(a1.w+b1.w)*vm};
      uint4 pk=pk8(f);
      u32 cb=(u32)(q*64+k*16);
      *(uint4*)((char*)hs+(u32)r*256+(cb^rowsw))=pk;
      hgp[r*16+q*4+k]=pk;
    }
  }
  __syncthreads();

  if(t<16){
    uint4 aR=*(const uint4*)((const char*)hs+(u32)t*16);
    uint4 bR=*(const uint4*)((const char*)hs+32*256+(u32)t*16);
    float fa[8],fb[8],fo[8];
    unp8(aR,fa); unp8(bR,fb);
    #pragma unroll
    for(int j=0;j<8;j++) fo[j]=0.5f*(fa[j]+fb[j]);
    ((uint4*)(hnOut+(size_t)blockIdx.x*H))[t]=pk8(fo);
  }
  {
    float ep=1.f+epsp[layer];
    #pragma unroll
    for(int p=0;p<4;p++){
      int i=t+p*256;
      u32 row=(u32)(i>>4), colb=(u32)((i&15)*16);
      u32 off=row*256+(colb^((row&7)<<4));
      float hf[8],o8[8];
      unp8(*(const uint4*)((const char*)hs+off),hf);
      #pragma unroll
      for(int j=0;j<8;j++) o8[j]=ep*hf[j];
      *(uint4*)((char*)agx+off)=pk8(o8);
    }
  }
  __syncthreads();

  {
    int slot=c>>4, chg=c&15;
    u32 cbyte=(u32)chg*16;
    int d0=slot*4;
    int s0=doff[grp][d0];
    int send=(d0+3==31)?n:doff[grp][d0+4];
    const u16* ep_=&epku[grp][0];
    auto LDP=[&](int p, uint4& hv, uint4& bv){
      u32 srow=(u32)(grp*32+(p>>9));
      u32 erow=(u32)(p&15);
      hv=*(const uint4*)((const char*)hs+srow*256+(cbyte^((srow&7)<<4)));
      bv=*(const uint4*)((const char*)bes+erow*256+(cbyte^((erow&7)<<4)));
    };
    auto FLUSH=[&](int cur, float* acc){
      u32 drow=(u32)(grp*32+cur);
      u32 aoff=drow*256+(cbyte^((drow&7)<<4));
      float of[8];
      unp8(*(const uint4*)((const char*)agx+aoff),of);
      #pragma unroll
      for(int q=0;q<8;q++) of[q]+=acc[q];
      *(uint4*)((char*)agx+aoff)=pk8(of);
    };
    float acc[8]={0.f,0.f,0.f,0.f,0.f,0.f,0.f,0.f};
    int cur=-1;
    uint4 hvA,bvA,hvB,bvB;
    hvA=bvA=hvB=bvB=make_uint4(0,0,0,0);
    int pA=0,pB=0;
    if(s0<send){ pA=ep_[s0]; LDP(pA,hvA,bvA); }
    if(s0+1<send){ pB=ep_[s0+1]; LDP(pB,hvB,bvB); }
    for(int j=s0;j<send;){
      {
        float hf[8],bf8[8];
        unp8(hvA,hf); unp8(bvA,bf8);
        int pc=pA;
        if(j+2<send){ pA=ep_[j+2]; LDP(pA,hvA,bvA); }
        int dl=(pc>>4)&31;
        if(dl!=cur){
          if(cur>=0) FLUSH(cur,acc);
          #pragma unroll
          for(int q=0;q<8;q++) acc[q]=0.f;
          cur=dl;
        }
        #pragma unroll
        for(int q=0;q<8;q++) acc[q]+=fmaxf(hf[q]+bf8[q],0.f);
      }
      j++;
      if(j>=send) break;
      {
        float hf[8],bf8[8];
        unp8(hvB,hf); unp8(bvB,bf8);
        int pc=pB;
        if(j+2<send){ pB=ep_[j+2]; LDP(pB,hvB,bvB); }
        int dl=(pc>>4)&31;
        if(dl!=cur){
          if(cur>=0) FLUSH(cur,acc);
          #pragma unroll
          for(int q=0;q<8;q++) acc[q]=0.f;
          cur=dl;
        }
        #pragma unroll
        for(int q=0;q<8;q++) acc[q]+=fmaxf(hf[q]+bf8[q],0.f);
      }
      j++;
    }
    if(cur>=0) FLUSH(cur,acc);
  }
  __syncthreads();
  sst[t]=0.f;
  __syncthreads();

  f32x4 a1[8];
  #pragma unroll
  for(int n8=0;n8<8;n8++) a1[n8]=(f32x4){0.f,0.f,0.f,0.f};
  #pragma unroll
  for(int kc=0;kc<4;kc++){
    u32 cb=(u32)((kc*32+lk*8)*2);
    s16x8 bf=*(const s16x8*)((char*)agx+(u32)rl*256+(cb^rsw));
    #pragma unroll
    for(int n8=0;n8<8;n8++){
      s16x8 af=*(const s16x8*)(W1p+((n8*4+kc)<<9)+lane*8);
      a1[n8]=__builtin_amdgcn_mfma_f32_16x16x32_bf16(af,bf,a1[n8],0,0,0);
    }
  }
  #pragma unroll
  for(int n8=0;n8<8;n8++){
    int c0=n8*16+lk*4;
    float4 b4=*(const float4*)(b1+c0);
    float v[4]={fmaxf(a1[n8][0]+b4.x,0.f),fmaxf(a1[n8][1]+b4.y,0.f),
                fmaxf(a1[n8][2]+b4.z,0.f),fmaxf(a1[n8][3]+b4.w,0.f)};
    *(uint2*)((char*)hs+(u32)rl*256+(((u32)(2*c0))^rsw))=pk4(v);
  }
  f32x4 a2[8];
  #pragma unroll
  for(int n8=0;n8<8;n8++) a2[n8]=(f32x4){0.f,0.f,0.f,0.f};
  #pragma unroll
  for(int kc=0;kc<4;kc++){
    u32 cb=(u32)((kc*32+lk*8)*2);
    s16x8 bf=*(const s16x8*)((char*)hs+(u32)rl*256+(cb^rsw));
    #pragma unroll
    for(int n8=0;n8<8;n8++){
      s16x8 af=*(const s16x8*)(W2p+((n8*4+kc)<<9)+lane*8);
      a2[n8]=__builtin_amdgcn_mfma_f32_16x16x32_bf16(af,bf,a2[n8],0,0,0);
    }
  }
  // epilogue: relu(+b2) -> agx (NO stats here)
  #pragma unroll
  for(int n8=0;n8<8;n8++){
    int c0=n8*16+lk*4;
    float4 b4=*(const float4*)(b2+c0);
    float v[4]={fmaxf(a2[n8][0]+b4.x,0.f),fmaxf(a2[n8][1]+b4.y,0.f),
                fmaxf(a2[n8][2]+b4.z,0.f),fmaxf(a2[n8][3]+b4.w,0.f)};
    *(uint2*)((char*)agx+(u32)rl*256+(((u32)(2*c0))^rsw))=pk4(v);
  }
  __syncthreads();
  // flush X + fused stats (fixed 8-column slice per thread)
  {
    float s8[8]={0,0,0,0,0,0,0,0}, q8[8]={0,0,0,0,0,0,0,0};
    uint4* out4=(uint4*)(Xg+hbase);
    #pragma unroll
    for(int p=0;p<4;p++){
      int i=t+p*256;
      u32 row=(u32)(i>>4), colb=(u32)((i&15)*16);
      uint4 v=*(const uint4*)((const char*)agx+row*256+(colb^((row&7)<<4)));
      out4[i]=v;
      float f[8];
      unp8(v,f);
      #pragma unroll
      for(int j=0;j<8;j++){ s8[j]+=f[j]; q8[j]+=f[j]*f[j]; }
    }
    #pragma unroll
    for(int j=0;j<8;j++){
      s8[j]+=__shfl_xor(s8[j],16); s8[j]+=__shfl_xor(s8[j],32);
      q8[j]+=__shfl_xor(q8[j],16); q8[j]+=__shfl_xor(q8[j],32);
    }
    if(lane<16){
      int cb8=(t&15)*8;
      #pragma unroll
      for(int j=0;j<8;j++){
        atomicAdd(&sst[cb8+j],s8[j]);
        atomicAdd(&sst[128+cb8+j],q8[j]);
      }
    }
  }
  __syncthreads();
  atomicAdd(&stats[t],sst[t]);
}

// ==== fused node path: global GINE agg (64 nodes) + 2-GEMM MLP + stats
__global__ __launch_bounds__(256) void k_node(
    const u16* __restrict__ hn, const u16* __restrict__ beb,
    const int* __restrict__ goff, const int* __restrict__ gcnt, const int* __restrict__ gpack,
    const float* __restrict__ epsp, int layer,
    const u16* __restrict__ W1p, const float* __restrict__ b1,
    const u16* __restrict__ W2p, const float* __restrict__ b2,
    u16* __restrict__ ag, float* __restrict__ stats)
{
  __shared__ u16 T[64*128];
  __shared__ u16 T2[64*128];
  __shared__ u16 bes[16*128];
  __shared__ float sst[256];
  int t=threadIdx.x;
  sst[t]=0.f;
  ((uint4*)bes)[t]=((const uint4*)beb)[t];
  __syncthreads();
  int node4=t>>2, q=t&3;
  int gnode=blockIdx.x*64+node4;
  float acc[32];
  float ep=1.f+epsp[layer];
  {
    const uint4* hrow=(const uint4*)(hn+(size_t)gnode*H+q*32);
    #pragma unroll
    for(int v=0;v<4;v++){
      float tmp[8];
      unp8(hrow[v],tmp);
      #pragma unroll
      for(int j=0;j<8;j++) acc[v*8+j]=ep*tmp[j];
    }
  }
  int o=goff[gnode], e=o+gcnt[gnode];
  for(;o<e;o++){
    int p=gpack[o];
    const uint4* srow=(const uint4*)(hn+(size_t)(p>>4)*H+q*32);
    const uint4* brow=(const uint4*)(bes+(p&15)*128+q*32);
    #pragma unroll
    for(int v=0;v<4;v++){
      float tmp[8],bf8[8];
      unp8(srow[v],tmp); unp8(brow[v],bf8);
      #pragma unroll
      for(int j=0;j<8;j++) acc[v*8+j]+=fmaxf(tmp[j]+bf8[j],0.f);
    }
  }
  {
    u32 rs=((u32)(node4&7))<<4;
    #pragma unroll
    for(int v=0;v<4;v++){
      u32 cb=(u32)((q*32+v*8)*2);
      *(uint4*)((char*)T+(u32)node4*256+(cb^rs))=pk8(&acc[v*8]);
    }
  }
  __syncthreads();
  int wave=t>>6, lane=t&63, lr=lane&15, lk=lane>>4;
  int rl=wave*16+lr;
  u32 rsw=((u32)(rl&7))<<4;
  int row0=blockIdx.x*64;
  f32x4 a1[8];
  #pragma unroll
  for(int n8=0;n8<8;n8++) a1[n8]=(f32x4){0.f,0.f,0.f,0.f};
  #pragma unroll
  for(int kc=0;kc<4;kc++){
    u32 cb=(u32)((kc*32+lk*8)*2);
    s16x8 bf=*(const s16x8*)((char*)T+(u32)rl*256+(cb^rsw));
    #pragma unroll
    for(int n8=0;n8<8;n8++){
      s16x8 af=*(const s16x8*)(W1p+((n8*4+kc)<<9)+lane*8);
      a1[n8]=__builtin_amdgcn_mfma_f32_16x16x32_bf16(af,bf,a1[n8],0,0,0);
    }
  }
  #pragma unroll
  for(int n8=0;n8<8;n8++){
    int c0=n8*16+lk*4;
    float4 b4=*(const float4*)(b1+c0);
    float v[4]={fmaxf(a1[n8][0]+b4.x,0.f),fmaxf(a1[n8][1]+b4.y,0.f),
                fmaxf(a1[n8][2]+b4.z,0.f),fmaxf(a1[n8][3]+b4.w,0.f)};
    *(uint2*)((char*)T2+(u32)rl*256+(((u32)(2*c0))^rsw))=pk4(v);
  }
  f32x4 a2[8];
  #pragma unroll
  for(int n8=0;n8<8;n8++) a2[n8]=(f32x4){0.f,0.f,0.f,0.f};
  #pragma unroll
  for(int kc=0;kc<4;kc++){
    u32 cb=(u32)((kc*32+lk*8)*2);
    s16x8 bf=*(const s16x8*)((char*)T2+(u32)rl*256+(cb^rsw));
    #pragma unroll
    for(int n8=0;n8<8;n8++){
      s16x8 af=*(const s16x8*)(W2p+((n8*4+kc)<<9)+lane*8);
      a2[n8]=__builtin_amdgcn_mfma_f32_16x16x32_bf16(af,bf,a2[n8],0,0,0);
    }
  }
  #pragma unroll
  for(int n8=0;n8<8;n8++){
    int c0=n8*16+lk*4;
    float4 b4=*(const float4*)(b2+c0);
    float v[4]={fmaxf(a2[n8][0]+b4.x,0.f),fmaxf(a2[n8][1]+b4.y,0.f),
                fmaxf(a2[n8][2]+b4.z,0.f),fmaxf(a2[n8][3]+b4.w,0.f)};
    *(uint2*)((char*)T+(u32)rl*256+(((u32)(2*c0))^rsw))=pk4(v);
  }
  __syncthreads();
  // flush + fused stats
  {
    float s8[8]={0,0,0,0,0,0,0,0}, q8[8]={0,0,0,0,0,0,0,0};
    uint4* out4=(uint4*)(ag+(size_t)row0*H);
    #pragma unroll
    for(int p=0;p<4;p++){
      int i=t+p*256;
      u32 row=(u32)(i>>4), colb=(u32)((i&15)*16);
      uint4 v=*(const uint4*)((const char*)T+row*256+(colb^((row&7)<<4)));
      out4[i]=v;
      float f[8];
      unp8(v,f);
      #pragma unroll
      for(int j=0;j<8;j++){ s8[j]+=f[j]; q8[j]+=f[j]*f[j]; }
    }
    #pragma unroll
    for(int j=0;j<8;j++){
      s8[j]+=__shfl_xor(s8[j],16); s8[j]+=__shfl_xor(s8[j],32);
      q8[j]+=__shfl_xor(q8[j],16); q8[j]+=__shfl_xor(q8[j],32);
    }
    if(lane<16){
      int cb8=(t&15)*8;
      #pragma unroll
      for(int j=0;j<8;j++){
        atomicAdd(&sst[cb8+j],s8[j]);
        atomicAdd(&sst[128+cb8+j],q8[j]);
      }
    }
  }
  __syncthreads();
  atomicAdd(&stats[t],sst[t]);
}

// ==== fused node broadcast: bb = ((hn + BN(ag)) @ bcw) @ cw1_bot
__global__ __launch_bounds__(256) void k_bcast(
    const u16* __restrict__ hn, const u16* __restrict__ ag,
    const float* __restrict__ stg, const float* __restrict__ gg, const float* __restrict__ bg,
    const u16* __restrict__ Wbcp, const u16* __restrict__ Wc1p,
    u16* __restrict__ bb)
{
  __shared__ u16 T[64*128];
  __shared__ u16 T2[64*128];
  __shared__ float ssh[128], tsh[128];
  int t=threadIdx.x;
  int row0=blockIdx.x*64;
  if(t<128){
    float mu=stg[t]*(1.f/4096.f);
    float var=stg[128+t]*(1.f/4096.f)-mu*mu;
    float s=gg[t]*rsqrtf(var+1e-5f);
    ssh[t]=s; tsh[t]=bg[t]-mu*s;
  }
  __syncthreads();
  #pragma unroll
  for(int i0=0;i0<4;i0++){
    int i=t+i0*256;
    u32 row=(u32)(i>>4);
    int cb8=(i&15)*8;
    float hv[8],av[8],o8[8];
    unp8(((const uint4*)(hn+(size_t)row0*H))[i],hv);
    unp8(((const uint4*)(ag+(size_t)row0*H))[i],av);
    #pragma unroll
    for(int j=0;j<8;j++) o8[j]=hv[j]+fmaf(av[j],ssh[cb8+j],tsh[cb8+j]);
    *(uint4*)((char*)T+row*256+(((u32)(cb8*2))^((row&7)<<4)))=pk8(o8);
  }
  __syncthreads();
  int wave=t>>6, lane=t&63, lr=lane&15, lk=lane>>4;
  int rl=wave*16+lr;
  u32 rsw=((u32)(rl&7))<<4;
  f32x4 a1[8];
  #pragma unroll
  for(int n8=0;n8<8;n8++) a1[n8]=(f32x4){0.f,0.f,0.f,0.f};
  #pragma unroll
  for(int kc=0;kc<4;kc++){
    u32 cb=(u32)((kc*32+lk*8)*2);
    s16x8 bf=*(const s16x8*)((char*)T+(u32)rl*256+(cb^rsw));
    #pragma unroll
    for(int n8=0;n8<8;n8++){
      s16x8 af=*(const s16x8*)(Wbcp+((n8*4+kc)<<9)+lane*8);
      a1[n8]=__builtin_amdgcn_mfma_f32_16x16x32_bf16(af,bf,a1[n8],0,0,0);
    }
  }
  #pragma unroll
  for(int n8=0;n8<8;n8++){
    int c0=n8*16+lk*4;
    float v[4]={a1[n8][0],a1[n8][1],a1[n8][2],a1[n8][3]};
    *(uint2*)((char*)T2+(u32)rl*256+(((u32)(2*c0))^rsw))=pk4(v);
  }
  f32x4 a2[8];
  #pragma unroll
  for(int n8=0;n8<8;n8++) a2[n8]=(f32x4){0.f,0.f,0.f,0.f};
  #pragma unroll
  for(int kc=0;kc<4;kc++){
    u32 cb=(u32)((kc*32+lk*8)*2);
    s16x8 bf=*(const s16x8*)((char*)T2+(u32)rl*256+(cb^rsw));
    #pragma unroll
    for(int n8=0;n8<8;n8++){
      s16x8 af=*(const s16x8*)(Wc1p+((n8*4+kc)<<9)+lane*8);
      a2[n8]=__builtin_amdgcn_mfma_f32_16x16x32_bf16(af,bf,a2[n8],0,0,0);
    }
  }
  #pragma unroll
  for(int n8=0;n8<8;n8++){
    int c0=n8*16+lk*4;
    float v[4]={a2[n8][0],a2[n8][1],a2[n8][2],a2[n8][3]};
    *(uint2*)((char*)T+(u32)rl*256+(((u32)(2*c0))^rsw))=pk4(v);
  }
  __syncthreads();
  uint4* out4=(uint4*)(bb+(size_t)row0*H);
  #pragma unroll
  for(int p=0;p<4;p++){
    int i=t+p*256;
    u32 row=(u32)(i>>4), colb=(u32)((i&15)*16);
    out4[i]=*(const uint4*)((const char*)T+row*256+(colb^((row&7)<<4)));
  }
}

// ==== final tail + pooling
__global__ __launch_bounds__(256) void k_tailpool(
    const u16* __restrict__ X, const u16* __restrict__ W3p, const float* __restrict__ bias3,
    const u16* __restrict__ bb,
    const u16* __restrict__ W2p, const float* __restrict__ cb2,
    const float* __restrict__ lng, const float* __restrict__ lnb,
    const int* __restrict__ validv, const u16* __restrict__ hres,
    const int* __restrict__ batch, float* __restrict__ oacc)
{
  __shared__ u16 T[64*128];
  __shared__ float pbuf[256];
  __shared__ float cntsh[2];
  int t=threadIdx.x;
  int wave=t>>6, lane=t&63, lr=lane&15, lk=lane>>4;
  int rl=wave*16+lr;
  u32 rsw=((u32)(rl&7))<<4;
  int row0=blockIdx.x*64;
  f32x4 acc[8];
  #pragma unroll
  for(int n8=0;n8<8;n8++) acc[n8]=(f32x4){0.f,0.f,0.f,0.f};
  const s16x8* B0=(const s16x8*)(X+(size_t)(row0+rl)*H);
  #pragma unroll
  for(int kc=0;kc<4;kc++){
    s16x8 bf=B0[kc*4+lk];
    #pragma unroll
    for(int n8=0;n8<8;n8++){
      s16x8 af=*(const s16x8*)(W3p+((n8*4+kc)<<9)+lane*8);
      acc[n8]=__builtin_amdgcn_mfma_f32_16x16x32_bf16(af,bf,acc[n8],0,0,0);
    }
  }
  #pragma unroll
  for(int n8=0;n8<8;n8++){
    int c0=n8*16+lk*4;
    float4 b4=*(const float4*)(bias3+c0);
    float rb[4];
    unp4(*(const uint2*)(bb+(size_t)blockIdx.x*H+c0),rb);
    float vb[4]={b4.x,b4.y,b4.z,b4.w};
    float v[4];
    #pragma unroll
    for(int j=0;j<4;j++){
      v[j]=gelu_f(acc[n8][j]+vb[j]+rb[j]);
    }
    *(uint2*)((char*)T+(u32)rl*256+(((u32)(2*c0))^rsw))=pk4(v);
  }
  f32x4 a2[8];
  #pragma unroll
  for(int n8=0;n8<8;n8++) a2[n8]=(f32x4){0.f,0.f,0.f,0.f};
  #pragma unroll
  for(int kc=0;kc<4;kc++){
    u32 cb=(u32)((kc*32+lk*8)*2);
    s16x8 bf=*(const s16x8*)((char*)T+(u32)rl*256+(cb^rsw));
    #pragma unroll
    for(int n8=0;n8<8;n8++){
      s16x8 af=*(const s16x8*)(W2p+((n8*4+kc)<<9)+lane*8);
      a2[n8]=__builtin_amdgcn_mfma_f32_16x16x32_bf16(af,bf,a2[n8],0,0,0);
    }
  }
  {
    float s=0.f,q=0.f;
    #pragma unroll
    for(int n8=0;n8<8;n8++){
      int c0=n8*16+lk*4;
      float4 b4=*(const float4*)(cb2+c0);
      float vb[4]={b4.x,b4.y,b4.z,b4.w};
      #pragma unroll
      for(int j=0;j<4;j++){
        float v=a2[n8][j]+vb[j];
        a2[n8][j]=v;
        s+=v; q+=v*v;
      }
    }
    s+=__shfl_xor(s,16); s+=__shfl_xor(s,32);
    q+=__shfl_xor(q,16); q+=__shfl_xor(q,32);
    float mu=s*(1.f/128.f);
    float rsig=rsqrtf(q*(1.f/128.f)-mu*mu+1e-5f);
    #pragma unroll
    for(int n8=0;n8<8;n8++){
      int c0=n8*16+lk*4;
      float4 g4=*(const float4*)(lng+c0);
      float4 e4=*(const float4*)(lnb+c0);
      float g[4]={g4.x,g4.y,g4.z,g4.w}, e[4]={e4.x,e4.y,e4.z,e4.w};
      float ov[4];
      #pragma unroll
      for(int j=0;j<4;j++) ov[j]=(a2[n8][j]-mu)*rsig*g[j]+e[j];
      *(uint2*)((char*)T+(u32)rl*256+(((u32)(2*c0))^rsw))=pk4(ov);
    }
  }
  pbuf[t]=0.f;
  if(t<2){
    int s=0;
    for(int j2=0;j2<32;j2++) s+=validv[row0+t*32+j2]?1:0;
    cntsh[t]=fmaxf((float)s,1.f);
  }
  __syncthreads();
  const uint4* hp=(const uint4*)(hres+(size_t)row0*H);
  float s0[8]={0,0,0,0,0,0,0,0}, s1[8]={0,0,0,0,0,0,0,0};
  #pragma unroll
  for(int p=0;p<4;p++){
    int i=t+p*256;
    u32 row=(u32)(i>>4), colb=(u32)((i&15)*16);
    int grow=row0+(int)row;
    uint4 v=*(const uint4*)((const char*)T+row*256+(colb^((row&7)<<4)));
    uint4 r=hp[i];
    float vv[8],rv[8];
    unp8(v,vv); unp8(r,rv);
    float vm=validv[grow]?1.f:0.f;
    #pragma unroll
    for(int j2=0;j2<8;j2++){
      float hh=(rv[j2]+vv[j2])*vm;
      if(p<2) s0[j2]+=hh; else s1[j2]+=hh;
    }
  }
  #pragma unroll
  for(int j2=0;j2<8;j2++){
    s0[j2]+=__shfl_xor(s0[j2],16); s0[j2]+=__shfl_xor(s0[j2],32);
    s1[j2]+=__shfl_xor(s1[j2],16); s1[j2]+=__shfl_xor(s1[j2],32);
  }
  if((lane&48)==0){
    int ch=(lane&15)*8;
    #pragma unroll
    for(int j2=0;j2<8;j2++){
      atomicAdd(&pbuf[ch+j2],s0[j2]);
      atomicAdd(&pbuf[128+ch+j2],s1[j2]);
    }
  }
  __syncthreads();
  if(t<128){
    float nodef=0.5f*(pbuf[t]/cntsh[0]+pbuf[128+t]/cntsh[1]);
    atomicAdd(&oacc[batch[blockIdx.x]*H+t],nodef);
  }
}

__global__ void k_out(const float* __restrict__ acc, const int* __restrict__ flag, void* __restrict__ out){
  int i=blockIdx.x*blockDim.x+threadIdx.x;
  if(i>=NGRAPH*H) return;
  if(*flag) ((__hip_bfloat16*)out)[i]=__float2bfloat16(acc[i]);
  else ((float*)out)[i]=acc[i];
}

extern "C" void kernel_launch(void* const* d_in, const int* in_sizes, int n_in,
                              void* d_out, int out_size, void* d_ws, size_t ws_size,
                              hipStream_t stream){
  (void)n_in; (void)out_size;
  int pofs[27]; pofs[0]=0;
  for(int i=0;i<26;i++) pofs[i+1]=pofs[i]+in_sizes[i];
  int ptot=pofs[26];

  char* wsb=(char*)d_ws;
  size_t off=0;
  auto alloc=[&](size_t bytes)->char*{ char* p=wsb+off; off+=(bytes+255)&~(size_t)255; return p; };
  int*   flag =(int*)  alloc(4);
  float* par  =(float*)alloc((size_t)ptot*4);
  u16*   h    =(u16*)  alloc((size_t)SKK*H*2);
  u16*   X    =(u16*)  alloc((size_t)SKK*H*2);
  u16*   wt   =(u16*)  alloc((size_t)28*HH*2);
  u16*   wt3  =(u16*)  alloc((size_t)HH*2);
  float* bias3=(float*)alloc(H*4);
  float* rf   =(float*)alloc((size_t)NN*H*4);
  u16*   bondb=(u16*)  alloc((size_t)16*H*2);
  u16*   hn   =(u16*)  alloc((size_t)NN*H*2);
  u16*   ag   =(u16*)  alloc((size_t)NN*H*2);
  u16*   bb   =(u16*)  alloc((size_t)NN*H*2);
  // ---- contiguous zero-init region ----
  int*   ecnt =(int*)  alloc(SS*4);
  int*   ecur =(int*)  alloc(SS*4);
  int*   gcnt =(int*)  alloc(NN*4);
  int*   gcur =(int*)  alloc(NN*4);
  float* stats=(float*)alloc(LNUM*512*4);
  float* oacc =(float*)alloc((size_t)NGRAPH*H*4);
  size_t zbytes=(size_t)SS*4+SS*4+NN*4+NN*4+LNUM*512*4+(size_t)NGRAPH*H*4;
  // ---- rest ----
  int* eoff  =(int*)alloc(SS*4);
  int* epack =(int*)alloc((size_t)EI*4);
  int* dstoff=(int*)alloc((size_t)SS*32*4);
  int* goff  =(int*)alloc(NN*4);
  int* gpack =(int*)alloc((size_t)EG*4);

  if(off>ws_size) return;

  const int* xids =(const int*)d_in[26];
  const int* iei  =(const int*)d_in[27];
  const int* iea  =(const int*)d_in[28];
  const int* gei  =(const int*)d_in[29];
  const int* gea  =(const int*)d_in[30];
  const int* nids =(const int*)d_in[31];
  const int* valid=(const int*)d_in[32];
  const int* batch=(const int*)d_in[33];

  const float* atom=par+pofs[0];
  const float* bond=par+pofs[1];
  const float* rw_w=par+pofs[2];
  const float* rw_b=par+pofs[3];
  const float* rwse=par+pofs[4];
  const float* leps=par+pofs[5];
  const float* lb1 =par+pofs[7];
  const float* lb2 =par+pofs[9];
  const float* lbng=par+pofs[10];
  const float* lbnb=par+pofs[11];
  const float* geps=par+pofs[12];
  const float* gb1 =par+pofs[14];
  const float* gb2 =par+pofs[16];
  const float* gbng=par+pofs[17];
  const float* gbnb=par+pofs[18];
  const float* cw1 =par+pofs[20];
  const float* cb1 =par+pofs[21];
  const float* cb2 =par+pofs[23];
  const float* lngp=par+pofs[24];
  const float* lnbp=par+pofs[25];

  k_sniff<<<1,256,0,stream>>>((const u16*)d_in[0], flag);
  CvtArgs ca;
  for(int i=0;i<26;i++){ ca.p[i]=d_in[i]; ca.start[i]=pofs[i]; }
  ca.start[26]=ptot;
  k_convert<<<1024,256,0,stream>>>(ca, flag, par);

  TransArgs ta;
  for(int l=0;l<LNUM;l++){
    ta.src[l*7+0]=pofs[6]+l*HH;
    ta.src[l*7+1]=pofs[8]+l*HH;
    ta.src[l*7+2]=pofs[13]+l*HH;
    ta.src[l*7+3]=pofs[15]+l*HH;
    ta.src[l*7+4]=pofs[19]+l*HH;
    ta.src[l*7+5]=pofs[20]+l*2*HH+HH;
    ta.src[l*7+6]=pofs[22]+l*HH;
  }
  k_trans<<<28,256,0,stream>>>(par, ta, wt);
  k_cvtbond<<<8,256,0,stream>>>(bond, bondb);

  (void)hipMemsetAsync(ecnt,0,zbytes,stream);

  k_hist<<<2048,256,0,stream>>>(iei+EI, EI, 5, ecnt);
  k_scan<<<1,1024,0,stream>>>(ecnt, eoff, SS);
  k_scatter_i<<<2048,256,0,stream>>>(iei, iea, eoff, ecur, epack);
  k_sortsub<<<SS,128,0,stream>>>(eoff, ecnt, epack, dstoff);
  k_hist<<<512,256,0,stream>>>(gei+EG, EG, 0, gcnt);
  k_scan<<<1,1024,0,stream>>>(gcnt, goff, NN);
  k_scatter_g<<<512,256,0,stream>>>(gei, gea, goff, gcur, gpack);

  k_rwse<<<NN,128,0,stream>>>(rwse, rw_w, rw_b, rf);

  for(int l=0;l<LNUM;l++){
    float* stl_l=stats+l*512;
    float* stg_l=stats+l*512+256;
    if(l==0){
      k_fused1<2><<<SS/2,256,0,stream>>>(h, bondb, eoff, ecnt, epack, dstoff, leps, l,
          wt+(size_t)(l*7+0)*HH, lb1+l*H, wt+(size_t)(l*7+1)*HH, lb2+l*H, X, stl_l,
          nullptr,nullptr,nullptr,nullptr,nullptr,nullptr,nullptr, valid, h,
          atom, rf, xids, nids, hn);
    } else {
      int pl=l-1;
      k_fused1<1><<<SS/2,256,0,stream>>>(h, bondb, eoff, ecnt, epack, dstoff, leps, l,
          wt+(size_t)(l*7+0)*HH, lb1+l*H, wt+(size_t)(l*7+1)*HH, lb2+l*H, X, stl_l,
          wt3, bias3, bb, wt+(size_t)(pl*7+6)*HH, cb2+pl*H,
          lngp+pl*H, lnbp+pl*H, valid, h,
          nullptr, nullptr, nullptr, nullptr, hn);
    }
    k_prepw3<<<128,128,0,stream>>>(cw1+(size_t)l*2*HH, cb1+l*H, stl_l, lbng+l*H, lbnb+l*H, wt3, bias3);
    k_node<<<NN/64,256,0,stream>>>(hn, bondb, goff, gcnt, gpack, geps, l,
        wt+(size_t)(l*7+2)*HH, gb1+l*H, wt+(size_t)(l*7+3)*HH, gb2+l*H, ag, stg_l);
    k_bcast<<<NN/64,256,0,stream>>>(hn, ag, stg_l, gbng+l*H, gbnb+l*H,
        wt+(size_t)(l*7+4)*HH, wt+(size_t)(l*7+5)*HH, bb);
  }
  {
    int l=LNUM-1;
    k_tailpool<<<SKK/64,256,0,stream>>>(X, wt3, bias3, bb,
        wt+(size_t)(l*7+6)*HH, cb2+l*H, lngp+l*H, lnbp+l*H, valid, h, batch, oacc);
  }
  k_out<<<(NGRAPH*H+255)/256,256,0,stream>>>(oacc, flag, d_out);
}

// Round 15
// 1187.336 us; speedup vs baseline: 1.0061x; 1.0061x over previous
//
#include <hip/hip_runtime.h>
#include <hip/hip_bf16.h>

#define H 128
#define HH 16384
#define LNUM 4
#define NN 4096
#define SS 8192
#define SKK 262144
#define EI 1048576
#define EG 65536
#define NGRAPH 64

typedef unsigned short u16;
typedef unsigned int u32;
typedef __attribute__((ext_vector_type(8))) short s16x8;
typedef __attribute__((ext_vector_type(4))) float f32x4;

__device__ __forceinline__ float b2f(u32 u){ return __uint_as_float(u<<16); }
__device__ __forceinline__ u16 f2b(float f){
  union { __hip_bfloat16 b; u16 u; } x;
  x.b=__float2bfloat16(f);
  return x.u;
}
__device__ __forceinline__ void unp8(uint4 v, float* f){
  f[0]=b2f(v.x&0xFFFF); f[1]=b2f(v.x>>16);
  f[2]=b2f(v.y&0xFFFF); f[3]=b2f(v.y>>16);
  f[4]=b2f(v.z&0xFFFF); f[5]=b2f(v.z>>16);
  f[6]=b2f(v.w&0xFFFF); f[7]=b2f(v.w>>16);
}
__device__ __forceinline__ void unp4(uint2 v, float* f){
  f[0]=b2f(v.x&0xFFFF); f[1]=b2f(v.x>>16);
  f[2]=b2f(v.y&0xFFFF); f[3]=b2f(v.y>>16);
}
// hardware packed f32->bf16 (RNE), lo=src0 hi=src1
__device__ __forceinline__ u32 cvtpk(float lo, float hi){
  u32 r;
  asm("v_cvt_pk_bf16_f32 %0,%1,%2":"=v"(r):"v"(lo),"v"(hi));
  return r;
}
__device__ __forceinline__ uint4 pk8(const float* f){
  uint4 r;
  r.x=cvtpk(f[0],f[1]);
  r.y=cvtpk(f[2],f[3]);
  r.z=cvtpk(f[4],f[5]);
  r.w=cvtpk(f[6],f[7]);
  return r;
}
__device__ __forceinline__ uint2 pk4(const float* f){
  uint2 r;
  r.x=cvtpk(f[0],f[1]);
  r.y=cvtpk(f[2],f[3]);
  return r;
}
// tanh-form gelu
__device__ __forceinline__ float gelu_f(float x){
  float u=x*(0.7978845608f+0.0356774081f*x*x);
  float ex=__expf(fminf(2.f*u,80.f));
  return x*(ex/(ex+1.f));
}

struct CvtArgs {
  const void* p[26];
  int start[27];
};
struct TransArgs { int src[28]; };

// ---- dtype sniff
__global__ void k_sniff(const u16* __restrict__ a, int* __restrict__ flag){
  __shared__ int cnt;
  if(threadIdx.x==0) cnt=0;
  __syncthreads();
  int big=0;
  for(int i=threadIdx.x;i<2048;i+=256){
    int e=(a[i]>>7)&0xFF;
    if(e>=127) big++;
  }
  atomicAdd(&cnt,big);
  __syncthreads();
  if(threadIdx.x==0) *flag=(cnt<16)?1:0;
}

__global__ void k_convert(CvtArgs args, const int* __restrict__ flag, float* __restrict__ dst){
  int fl=*flag;
  int total=args.start[26];
  for(int i=blockIdx.x*blockDim.x+threadIdx.x;i<total;i+=gridDim.x*blockDim.x){
    int a=0;
    while(args.start[a+1]<=i) a++;
    int j=i-args.start[a];
    float v;
    if(fl) v=b2f(((const u16*)args.p[a])[j]);
    else   v=((const float*)args.p[a])[j];
    dst[i]=v;
  }
}

// ---- static weights: f32 [K][N] -> bf16 fragment-major packed
__global__ __launch_bounds__(256) void k_trans(const float* __restrict__ par, TransArgs ta, u16* __restrict__ wt){
  const float* s=par+ta.src[blockIdx.x];
  u16* d=wt+(size_t)blockIdx.x*HH;
  for(int i=threadIdx.x;i<HH;i+=256){
    int j=i&7, lane=(i>>3)&63, fc=i>>9;
    int n=fc>>2, kc=fc&3, lr=lane&15, lk=lane>>4;
    int outc=n*16+lr, k=kc*32+lk*8+j;
    d[i]=f2b(s[(size_t)k*H+outc]);
  }
}

// ---- bond emb f32 -> bf16
__global__ void k_cvtbond(const float* __restrict__ b, u16* __restrict__ bb){
  int i=blockIdx.x*blockDim.x+threadIdx.x;
  if(i<16*H) bb[i]=f2b(b[i]);
}

// ---- fold local-BN affine into cw1_top, packed output
__global__ __launch_bounds__(128) void k_prepw3(const float* __restrict__ w, const float* __restrict__ cb1,
                        const float* __restrict__ stl, const float* __restrict__ gl, const float* __restrict__ bl,
                        u16* __restrict__ wt3p, float* __restrict__ bias3){
  __shared__ float red[128];
  int c=blockIdx.x, k=threadIdx.x;
  float mu=stl[k]*(1.f/262144.f);
  float var=stl[128+k]*(1.f/262144.f)-mu*mu;
  float s=gl[k]*rsqrtf(var+1e-5f);
  float tt=bl[k]-mu*s;
  float wv=w[(size_t)k*H+c];
  int idx=(((c>>4)*4+(k>>5))*64+((k>>3)&3)*16+(c&15))*8+(k&7);
  wt3p[idx]=f2b(s*wv);
  red[k]=tt*wv;
  __syncthreads();
  for(int d=64;d>0;d>>=1){ if(k<d) red[k]+=red[k+d]; __syncthreads(); }
  if(k==0) bias3[c]=cb1[c]+red[0];
}

// ---- edge bucketing
__global__ void k_hist(const int* __restrict__ idx, int n, int shift, int* __restrict__ cnt){
  for(int i=blockIdx.x*blockDim.x+threadIdx.x;i<n;i+=gridDim.x*blockDim.x)
    atomicAdd(&cnt[idx[i]>>shift],1);
}

__global__ void k_scan(const int* __restrict__ cnt, int* __restrict__ off, int nbins){
  __shared__ int ts[1024];
  int t=threadIdx.x;
  int per=nbins>>10;
  int base=t*per;
  int s=0;
  for(int j=0;j<per;j++) s+=cnt[base+j];
  ts[t]=s;
  __syncthreads();
  for(int d=1;d<1024;d<<=1){
    int v=(t>=d)?ts[t-d]:0;
    __syncthreads();
    ts[t]+=v;
    __syncthreads();
  }
  int ex=(t==0)?0:ts[t-1];
  for(int j=0;j<per;j++){ off[base+j]=ex; ex+=cnt[base+j]; }
}

__global__ void k_scatter_i(const int* __restrict__ ei, const int* __restrict__ ea,
                            const int* __restrict__ off, int* __restrict__ cur, int* __restrict__ pack){
  for(int i=blockIdx.x*blockDim.x+threadIdx.x;i<EI;i+=gridDim.x*blockDim.x){
    int s=ei[i], d=ei[EI+i];
    int sub=d>>5;
    int pos=off[sub]+atomicAdd(&cur[sub],1);
    pack[pos]=((s&31)<<9)|((d&31)<<4)|(ea[i]&15);
  }
}

// ---- sort each subgraph's edges by dst-lane; persist per-dst segment starts
__global__ __launch_bounds__(128) void k_sortsub(const int* __restrict__ eoff, const int* __restrict__ ecnt,
                                                 int* __restrict__ epack, int* __restrict__ dstoff){
  __shared__ int ein[512];
  __shared__ int eout[512];
  __shared__ int bcnt[32];
  __shared__ int bpos[32];
  int sub=blockIdx.x, t=threadIdx.x;
  int o=eoff[sub];
  int n=ecnt[sub]; if(n>512) n=512;
  for(int i=t;i<n;i+=128) ein[i]=epack[o+i];
  if(t<32) bcnt[t]=0;
  __syncthreads();
  for(int i=t;i<n;i+=128) atomicAdd(&bcnt[(ein[i]>>4)&31],1);
  __syncthreads();
  if(t==0){
    int s=0;
    for(int b=0;b<32;b++){ bpos[b]=s; s+=bcnt[b]; }
  }
  __syncthreads();
  if(t<32) dstoff[sub*32+t]=bpos[t];
  __syncthreads();
  for(int i=t;i<n;i+=128){
    int p=ein[i];
    int pos=atomicAdd(&bpos[(p>>4)&31],1);
    eout[pos]=p;
  }
  __syncthreads();
  for(int i=t;i<n;i+=128) epack[o+i]=eout[i];
}

__global__ void k_scatter_g(const int* __restrict__ ei, const int* __restrict__ ea,
                            const int* __restrict__ off, int* __restrict__ cur, int* __restrict__ pack){
  for(int i=blockIdx.x*blockDim.x+threadIdx.x;i<EG;i+=gridDim.x*blockDim.x){
    int s=ei[i], d=ei[EG+i];
    int pos=off[d]+atomicAdd(&cur[d],1);
    pack[pos]=(s<<4)|(ea[i]&15);
  }
}

// ---- rf = relu(rwse @ rwse_w + rwse_b)
__global__ __launch_bounds__(128) void k_rwse(const float* __restrict__ rwse, const float* __restrict__ w,
                      const float* __restrict__ b, float* __restrict__ rf){
  __shared__ float ws[16*128];
  __shared__ float rv[16];
  int n=blockIdx.x, c=threadIdx.x;
  for(int i=c;i<2048;i+=128) ws[i]=w[i];
  if(c<16) rv[c]=rwse[n*16+c];
  __syncthreads();
  float acc=b[c];
  for(int j=0;j<16;j++) acc=fmaf(rv[j],ws[j*128+c],acc);
  rf[(size_t)n*H+c]=fmaxf(acc,0.f);
}

// ==== FUSED mega-kernel. MODE 1: prev-layer tail first. MODE 2: build h0 in-block.
template<int MODE>
__global__ __launch_bounds__(256,4) void k_fused1(
    const u16* __restrict__ h, const u16* __restrict__ beb,
    const int* __restrict__ eoff, const int* __restrict__ ecnt, const int* __restrict__ epack,
    const int* __restrict__ dstoff,
    const float* __restrict__ epsp, int layer,
    const u16* __restrict__ W1p, const float* __restrict__ b1,
    const u16* __restrict__ W2p, const float* __restrict__ b2,
    u16* __restrict__ Xg, float* __restrict__ stats,
    const u16* __restrict__ W3p, const float* __restrict__ bias3,
    const u16* __restrict__ bbv,
    const u16* __restrict__ Wc2p, const float* __restrict__ cb2,
    const float* __restrict__ lng, const float* __restrict__ lnb,
    const int* __restrict__ validv, u16* __restrict__ hio,
    const float* __restrict__ atomp, const float* __restrict__ rfp,
    const int* __restrict__ xids, const int* __restrict__ nids,
    u16* __restrict__ hnOut)
{
  __shared__ u16 hs[64*128];
  __shared__ u16 agx[64*128];
  __shared__ u16 bes[16*128];
  __shared__ u16 epku[2][512];
  __shared__ int doff[2][32];
  float* sst=(float*)&epku[0][0];

  int t=threadIdx.x;
  int grp=t>>7, c=t&127;
  size_t hbase=(size_t)blockIdx.x*64*H;
  int wave=t>>6, lane=t&63, lr=lane&15, lk=lane>>4;
  int rl=wave*16+lr;
  u32 rsw=((u32)(rl&7))<<4;
  int row0=blockIdx.x*64;

  {
    u32 row=(u32)(t>>4), colb=(u32)((t&15)*16);
    *(uint4*)((char*)bes+row*256+(colb^((row&7)<<4)))=((const uint4*)beb)[t];
  }
  int sub=blockIdx.x*2+grp;
  int n=min(ecnt[sub],512);
  int o=eoff[sub];
  if(c<32) doff[grp][c]=dstoff[sub*32+c];
  for(int i=c;i<n;i+=128) epku[grp][i]=(u16)epack[o+i];

  if(MODE==1){
    f32x4 a1t[8];
    #pragma unroll
    for(int n8=0;n8<8;n8++) a1t[n8]=(f32x4){0.f,0.f,0.f,0.f};
    const s16x8* B0=(const s16x8*)(Xg+(size_t)(row0+rl)*H);
    #pragma unroll
    for(int kc=0;kc<4;kc++){
      s16x8 bf=B0[kc*4+lk];
      #pragma unroll
      for(int n8=0;n8<8;n8++){
        s16x8 af=*(const s16x8*)(W3p+((n8*4+kc)<<9)+lane*8);
        a1t[n8]=__builtin_amdgcn_mfma_f32_16x16x32_bf16(af,bf,a1t[n8],0,0,0);
      }
    }
    #pragma unroll
    for(int n8=0;n8<8;n8++){
      int c0=n8*16+lk*4;
      float4 b4=*(const float4*)(bias3+c0);
      float rb[4];
      unp4(*(const uint2*)(bbv+(size_t)blockIdx.x*H+c0),rb);
      float vb[4]={b4.x,b4.y,b4.z,b4.w};
      float v[4];
      #pragma unroll
      for(int j=0;j<4;j++){
        v[j]=gelu_f(a1t[n8][j]+vb[j]+rb[j]);
      }
      *(uint2*)((char*)agx+(u32)rl*256+(((u32)(2*c0))^rsw))=pk4(v);
    }
    f32x4 a2t[8];
    #pragma unroll
    for(int n8=0;n8<8;n8++) a2t[n8]=(f32x4){0.f,0.f,0.f,0.f};
    #pragma unroll
    for(int kc=0;kc<4;kc++){
      u32 cb=(u32)((kc*32+lk*8)*2);
      s16x8 bf=*(const s16x8*)((char*)agx+(u32)rl*256+(cb^rsw));
      #pragma unroll
      for(int n8=0;n8<8;n8++){
        s16x8 af=*(const s16x8*)(Wc2p+((n8*4+kc)<<9)+lane*8);
        a2t[n8]=__builtin_amdgcn_mfma_f32_16x16x32_bf16(af,bf,a2t[n8],0,0,0);
      }
    }
    {
      float s=0.f,q=0.f;
      #pragma unroll
      for(int n8=0;n8<8;n8++){
        int c0=n8*16+lk*4;
        float4 b4=*(const float4*)(cb2+c0);
        float vb[4]={b4.x,b4.y,b4.z,b4.w};
        #pragma unroll
        for(int j=0;j<4;j++){
          float v=a2t[n8][j]+vb[j];
          a2t[n8][j]=v;
          s+=v; q+=v*v;
        }
      }
      s+=__shfl_xor(s,16); s+=__shfl_xor(s,32);
      q+=__shfl_xor(q,16); q+=__shfl_xor(q,32);
      float mu=s*(1.f/128.f);
      float rsig=rsqrtf(q*(1.f/128.f)-mu*mu+1e-5f);
      #pragma unroll
      for(int n8=0;n8<8;n8++){
        int c0=n8*16+lk*4;
        float4 g4=*(const float4*)(lng+c0);
        float4 e4=*(const float4*)(lnb+c0);
        float g[4]={g4.x,g4.y,g4.z,g4.w}, e[4]={e4.x,e4.y,e4.z,e4.w};
        float ov[4];
        #pragma unroll
        for(int j=0;j<4;j++) ov[j]=(a2t[n8][j]-mu)*rsig*g[j]+e[j];
        *(uint2*)((char*)agx+(u32)rl*256+(((u32)(2*c0))^rsw))=pk4(ov);
      }
    }
    __syncthreads();
    uint4* hp=(uint4*)(hio+hbase);
    #pragma unroll
    for(int p=0;p<4;p++){
      int i=t+p*256;
      u32 row=(u32)(i>>4), colb=(u32)((i&15)*16);
      int grow=row0+(int)row;
      uint4 v=*(const uint4*)((const char*)agx+row*256+(colb^((row&7)<<4)));
      uint4 r=hp[i];
      float vv[8],rv[8],o8[8];
      unp8(v,vv); unp8(r,rv);
      float vm=validv[grow]?1.f:0.f;
      #pragma unroll
      for(int j=0;j<8;j++) o8[j]=(rv[j]+vv[j])*vm;
      uint4 pk=pk8(o8);
      hp[i]=pk;
      *(uint4*)((char*)hs+row*256+(colb^((row&7)<<4)))=pk;
    }
  } else {
    int r=t>>2, q=t&3;
    int grow=row0+r;
    float vm=validv[grow]?1.f:0.f;
    const float4* ap=(const float4*)(atomp+(size_t)xids[grow]*H)+q*8;
    const float4* bp=(const float4*)(rfp+(size_t)nids[grow]*H)+q*8;
    u32 rowsw=((u32)(r&7))<<4;
    uint4* hgp=(uint4*)(hio+hbase);
    #pragma unroll
    for(int k=0;k<4;k++){
      float4 a0=ap[k*2], a1=ap[k*2+1], b0=bp[k*2], b1=bp[k*2+1];
      float f[8]={(a0.x+b0.x)*vm,(a0.y+b0.y)*vm,(a0.z+b0.z)*vm,(a0.w+b0.w)*vm,
                  (a1.x+b1.x)*vm,(a1.y+b1.y)*vm,(a1.z+b1.z)*vm,(a1.w+b1.w)*vm};
      uint4 pk=pk8(f);
      u32 cb=(u32)(q*64+k*16);
      *(uint4*)((char*)hs+(u32)r*256+(cb^rowsw))=pk;
      hgp[r*16+q*4+k]=pk;
    }
  }
  __syncthreads();

  if(t<16){
    uint4 aR=*(const uint4*)((const char*)hs+(u32)t*16);
    uint4 bR=*(const uint4*)((const char*)hs+32*256+(u32)t*16);
    float fa[8],fb[8],fo[8];
    unp8(aR,fa); unp8(bR,fb);
    #pragma unroll
    for(int j=0;j<8;j++) fo[j]=0.5f*(fa[j]+fb[j]);
    ((uint4*)(hnOut+(size_t)blockIdx.x*H))[t]=pk8(fo);
  }
  {
    float ep=1.f+epsp[layer];
    #pragma unroll
    for(int p=0;p<4;p++){
      int i=t+p*256;
      u32 row=(u32)(i>>4), colb=(u32)((i&15)*16);
      u32 off=row*256+(colb^((row&7)<<4));
      float hf[8],o8[8];
      unp8(*(const uint4*)((const char*)hs+off),hf);
      #pragma unroll
      for(int j=0;j<8;j++) o8[j]=ep*hf[j];
      *(uint4*)((char*)agx+off)=pk8(o8);
    }
  }
  __syncthreads();

  {
    int slot=c>>4, chg=c&15;
    u32 cbyte=(u32)chg*16;
    int d0=slot*4;
    int s0=doff[grp][d0];
    int send=(d0+3==31)?n:doff[grp][d0+4];
    const u16* ep_=&epku[grp][0];
    auto LDP=[&](int p, uint4& hv, uint4& bv){
      u32 srow=(u32)(grp*32+(p>>9));
      u32 erow=(u32)(p&15);
      hv=*(const uint4*)((const char*)hs+srow*256+(cbyte^((srow&7)<<4)));
      bv=*(const uint4*)((const char*)bes+erow*256+(cbyte^((erow&7)<<4)));
    };
    auto FLUSH=[&](int cur, float* acc){
      u32 drow=(u32)(grp*32+cur);
      u32 aoff=drow*256+(cbyte^((drow&7)<<4));
      float of[8];
      unp8(*(const uint4*)((const char*)agx+aoff),of);
      #pragma unroll
      for(int q=0;q<8;q++) of[q]+=acc[q];
      *(uint4*)((char*)agx+aoff)=pk8(of);
    };
    float acc[8]={0.f,0.f,0.f,0.f,0.f,0.f,0.f,0.f};
    int cur=-1;
    uint4 hvA,bvA,hvB,bvB;
    hvA=bvA=hvB=bvB=make_uint4(0,0,0,0);
    int pA=0,pB=0;
    if(s0<send){ pA=ep_[s0]; LDP(pA,hvA,bvA); }
    if(s0+1<send){ pB=ep_[s0+1]; LDP(pB,hvB,bvB); }
    for(int j=s0;j<send;){
      {
        float hf[8],bf8[8];
        unp8(hvA,hf); unp8(bvA,bf8);
        int pc=pA;
        if(j+2<send){ pA=ep_[j+2]; LDP(pA,hvA,bvA); }
        int dl=(pc>>4)&31;
        if(dl!=cur){
          if(cur>=0) FLUSH(cur,acc);
          #pragma unroll
          for(int q=0;q<8;q++) acc[q]=0.f;
          cur=dl;
        }
        #pragma unroll
        for(int q=0;q<8;q++) acc[q]+=fmaxf(hf[q]+bf8[q],0.f);
      }
      j++;
      if(j>=send) break;
      {
        float hf[8],bf8[8];
        unp8(hvB,hf); unp8(bvB,bf8);
        int pc=pB;
        if(j+2<send){ pB=ep_[j+2]; LDP(pB,hvB,bvB); }
        int dl=(pc>>4)&31;
        if(dl!=cur){
          if(cur>=0) FLUSH(cur,acc);
          #pragma unroll
          for(int q=0;q<8;q++) acc[q]=0.f;
          cur=dl;
        }
        #pragma unroll
        for(int q=0;q<8;q++) acc[q]+=fmaxf(hf[q]+bf8[q],0.f);
      }
      j++;
    }
    if(cur>=0) FLUSH(cur,acc);
  }
  __syncthreads();
  sst[t]=0.f;
  __syncthreads();

  f32x4 a1[8];
  #pragma unroll
  for(int n8=0;n8<8;n8++) a1[n8]=(f32x4){0.f,0.f,0.f,0.f};
  #pragma unroll
  for(int kc=0;kc<4;kc++){
    u32 cb=(u32)((kc*32+lk*8)*2);
    s16x8 bf=*(const s16x8*)((char*)agx+(u32)rl*256+(cb^rsw));
    #pragma unroll
    for(int n8=0;n8<8;n8++){
      s16x8 af=*(const s16x8*)(W1p+((n8*4+kc)<<9)+lane*8);
      a1[n8]=__builtin_amdgcn_mfma_f32_16x16x32_bf16(af,bf,a1[n8],0,0,0);
    }
  }
  #pragma unroll
  for(int n8=0;n8<8;n8++){
    int c0=n8*16+lk*4;
    float4 b4=*(const float4*)(b1+c0);
    float v[4]={fmaxf(a1[n8][0]+b4.x,0.f),fmaxf(a1[n8][1]+b4.y,0.f),
                fmaxf(a1[n8][2]+b4.z,0.f),fmaxf(a1[n8][3]+b4.w,0.f)};
    *(uint2*)((char*)hs+(u32)rl*256+(((u32)(2*c0))^rsw))=pk4(v);
  }
  f32x4 a2[8];
  #pragma unroll
  for(int n8=0;n8<8;n8++) a2[n8]=(f32x4){0.f,0.f,0.f,0.f};
  #pragma unroll
  for(int kc=0;kc<4;kc++){
    u32 cb=(u32)((kc*32+lk*8)*2);
    s16x8 bf=*(const s16x8*)((char*)hs+(u32)rl*256+(cb^rsw));
    #pragma unroll
    for(int n8=0;n8<8;n8++){
      s16x8 af=*(const s16x8*)(W2p+((n8*4+kc)<<9)+lane*8);
      a2[n8]=__builtin_amdgcn_mfma_f32_16x16x32_bf16(af,bf,a2[n8],0,0,0);
    }
  }
  // epilogue: relu(+b2) -> agx + stats (round-13 proven form)
  #pragma unroll
  for(int n8=0;n8<8;n8++){
    int c0=n8*16+lk*4;
    float4 b4=*(const float4*)(b2+c0);
    float v[4]={fmaxf(a2[n8][0]+b4.x,0.f),fmaxf(a2[n8][1]+b4.y,0.f),
                fmaxf(a2[n8][2]+b4.z,0.f),fmaxf(a2[n8][3]+b4.w,0.f)};
    *(uint2*)((char*)agx+(u32)rl*256+(((u32)(2*c0))^rsw))=pk4(v);
    float s[4],q[4];
    #pragma unroll
    for(int j2=0;j2<4;j2++){ s[j2]=v[j2]; q[j2]=v[j2]*v[j2]; }
    #pragma unroll
    for(int j2=0;j2<4;j2++){
      #pragma unroll
      for(int d=1;d<16;d<<=1){
        s[j2]+=__shfl_xor(s[j2],d);
        q[j2]+=__shfl_xor(q[j2],d);
      }
    }
    if(lr==0){
      #pragma unroll
      for(int j2=0;j2<4;j2++){
        atomicAdd(&sst[c0+j2],s[j2]);
        atomicAdd(&sst[128+c0+j2],q[j2]);
      }
    }
  }
  __syncthreads();
  uint4* out4=(uint4*)(Xg+hbase);
  #pragma unroll
  for(int p=0;p<4;p++){
    int i=t+p*256;
    u32 row=(u32)(i>>4), colb=(u32)((i&15)*16);
    out4[i]=*(const uint4*)((const char*)agx+row*256+(colb^((row&7)<<4)));
  }
  atomicAdd(&stats[t],sst[t]);
}

// ==== fused node path: global GINE agg (64 nodes) + 2-GEMM MLP + stats
__global__ __launch_bounds__(256) void k_node(
    const u16* __restrict__ hn, const u16* __restrict__ beb,
    const int* __restrict__ goff, const int* __restrict__ gcnt, const int* __restrict__ gpack,
    const float* __restrict__ epsp, int layer,
    const u16* __restrict__ W1p, const float* __restrict__ b1,
    const u16* __restrict__ W2p, const float* __restrict__ b2,
    u16* __restrict__ ag, float* __restrict__ stats)
{
  __shared__ u16 T[64*128];
  __shared__ u16 T2[64*128];
  __shared__ u16 bes[16*128];
  __shared__ float sst[256];
  int t=threadIdx.x;
  sst[t]=0.f;
  ((uint4*)bes)[t]=((const uint4*)beb)[t];
  __syncthreads();
  int node4=t>>2, q=t&3;
  int gnode=blockIdx.x*64+node4;
  float acc[32];
  float ep=1.f+epsp[layer];
  {
    const uint4* hrow=(const uint4*)(hn+(size_t)gnode*H+q*32);
    #pragma unroll
    for(int v=0;v<4;v++){
      float tmp[8];
      unp8(hrow[v],tmp);
      #pragma unroll
      for(int j=0;j<8;j++) acc[v*8+j]=ep*tmp[j];
    }
  }
  int o=goff[gnode], e=o+gcnt[gnode];
  for(;o<e;o++){
    int p=gpack[o];
    const uint4* srow=(const uint4*)(hn+(size_t)(p>>4)*H+q*32);
    const uint4* brow=(const uint4*)(bes+(p&15)*128+q*32);
    #pragma unroll
    for(int v=0;v<4;v++){
      float tmp[8],bf8[8];
      unp8(srow[v],tmp); unp8(brow[v],bf8);
      #pragma unroll
      for(int j=0;j<8;j++) acc[v*8+j]+=fmaxf(tmp[j]+bf8[j],0.f);
    }
  }
  {
    u32 rs=((u32)(node4&7))<<4;
    #pragma unroll
    for(int v=0;v<4;v++){
      u32 cb=(u32)((q*32+v*8)*2);
      *(uint4*)((char*)T+(u32)node4*256+(cb^rs))=pk8(&acc[v*8]);
    }
  }
  __syncthreads();
  int wave=t>>6, lane=t&63, lr=lane&15, lk=lane>>4;
  int rl=wave*16+lr;
  u32 rsw=((u32)(rl&7))<<4;
  int row0=blockIdx.x*64;
  f32x4 a1[8];
  #pragma unroll
  for(int n8=0;n8<8;n8++) a1[n8]=(f32x4){0.f,0.f,0.f,0.f};
  #pragma unroll
  for(int kc=0;kc<4;kc++){
    u32 cb=(u32)((kc*32+lk*8)*2);
    s16x8 bf=*(const s16x8*)((char*)T+(u32)rl*256+(cb^rsw));
    #pragma unroll
    for(int n8=0;n8<8;n8++){
      s16x8 af=*(const s16x8*)(W1p+((n8*4+kc)<<9)+lane*8);
      a1[n8]=__builtin_amdgcn_mfma_f32_16x16x32_bf16(af,bf,a1[n8],0,0,0);
    }
  }
  #pragma unroll
  for(int n8=0;n8<8;n8++){
    int c0=n8*16+lk*4;
    float4 b4=*(const float4*)(b1+c0);
    float v[4]={fmaxf(a1[n8][0]+b4.x,0.f),fmaxf(a1[n8][1]+b4.y,0.f),
                fmaxf(a1[n8][2]+b4.z,0.f),fmaxf(a1[n8][3]+b4.w,0.f)};
    *(uint2*)((char*)T2+(u32)rl*256+(((u32)(2*c0))^rsw))=pk4(v);
  }
  f32x4 a2[8];
  #pragma unroll
  for(int n8=0;n8<8;n8++) a2[n8]=(f32x4){0.f,0.f,0.f,0.f};
  #pragma unroll
  for(int kc=0;kc<4;kc++){
    u32 cb=(u32)((kc*32+lk*8)*2);
    s16x8 bf=*(const s16x8*)((char*)T2+(u32)rl*256+(cb^rsw));
    #pragma unroll
    for(int n8=0;n8<8;n8++){
      s16x8 af=*(const s16x8*)(W2p+((n8*4+kc)<<9)+lane*8);
      a2[n8]=__builtin_amdgcn_mfma_f32_16x16x32_bf16(af,bf,a2[n8],0,0,0);
    }
  }
  #pragma unroll
  for(int n8=0;n8<8;n8++){
    int c0=n8*16+lk*4;
    float4 b4=*(const float4*)(b2+c0);
    float v[4]={fmaxf(a2[n8][0]+b4.x,0.f),fmaxf(a2[n8][1]+b4.y,0.f),
                fmaxf(a2[n8][2]+b4.z,0.f),fmaxf(a2[n8][3]+b4.w,0.f)};
    *(uint2*)((char*)T+(u32)rl*256+(((u32)(2*c0))^rsw))=pk4(v);
    float s[4],qq[4];
    #pragma unroll
    for(int j=0;j<4;j++){ s[j]=v[j]; qq[j]=v[j]*v[j]; }
    #pragma unroll
    for(int j=0;j<4;j++){
      #pragma unroll
      for(int d=1;d<16;d<<=1){
        s[j]+=__shfl_xor(s[j],d);
        qq[j]+=__shfl_xor(qq[j],d);
      }
    }
    if(lr==0){
      #pragma unroll
      for(int j=0;j<4;j++){
        atomicAdd(&sst[c0+j],s[j]);
        atomicAdd(&sst[128+c0+j],qq[j]);
      }
    }
  }
  __syncthreads();
  uint4* out4=(uint4*)(ag+(size_t)row0*H);
  #pragma unroll
  for(int p=0;p<4;p++){
    int i=t+p*256;
    u32 row=(u32)(i>>4), colb=(u32)((i&15)*16);
    out4[i]=*(const uint4*)((const char*)T+row*256+(colb^((row&7)<<4)));
  }
  atomicAdd(&stats[t],sst[t]);
}

// ==== fused node broadcast: bb = ((hn + BN(ag)) @ bcw) @ cw1_bot
__global__ __launch_bounds__(256) void k_bcast(
    const u16* __restrict__ hn, const u16* __restrict__ ag,
    const float* __restrict__ stg, const float* __restrict__ gg, const float* __restrict__ bg,
    const u16* __restrict__ Wbcp, const u16* __restrict__ Wc1p,
    u16* __restrict__ bb)
{
  __shared__ u16 T[64*128];
  __shared__ u16 T2[64*128];
  __shared__ float ssh[128], tsh[128];
  int t=threadIdx.x;
  int row0=blockIdx.x*64;
  if(t<128){
    float mu=stg[t]*(1.f/4096.f);
    float var=stg[128+t]*(1.f/4096.f)-mu*mu;
    float s=gg[t]*rsqrtf(var+1e-5f);
    ssh[t]=s; tsh[t]=bg[t]-mu*s;
  }
  __syncthreads();
  #pragma unroll
  for(int i0=0;i0<4;i0++){
    int i=t+i0*256;
    u32 row=(u32)(i>>4);
    int cb8=(i&15)*8;
    float hv[8],av[8],o8[8];
    unp8(((const uint4*)(hn+(size_t)row0*H))[i],hv);
    unp8(((const uint4*)(ag+(size_t)row0*H))[i],av);
    #pragma unroll
    for(int j=0;j<8;j++) o8[j]=hv[j]+fmaf(av[j],ssh[cb8+j],tsh[cb8+j]);
    *(uint4*)((char*)T+row*256+(((u32)(cb8*2))^((row&7)<<4)))=pk8(o8);
  }
  __syncthreads();
  int wave=t>>6, lane=t&63, lr=lane&15, lk=lane>>4;
  int rl=wave*16+lr;
  u32 rsw=((u32)(rl&7))<<4;
  f32x4 a1[8];
  #pragma unroll
  for(int n8=0;n8<8;n8++) a1[n8]=(f32x4){0.f,0.f,0.f,0.f};
  #pragma unroll
  for(int kc=0;kc<4;kc++){
    u32 cb=(u32)((kc*32+lk*8)*2);
    s16x8 bf=*(const s16x8*)((char*)T+(u32)rl*256+(cb^rsw));
    #pragma unroll
    for(int n8=0;n8<8;n8++){
      s16x8 af=*(const s16x8*)(Wbcp+((n8*4+kc)<<9)+lane*8);
      a1[n8]=__builtin_amdgcn_mfma_f32_16x16x32_bf16(af,bf,a1[n8],0,0,0);
    }
  }
  #pragma unroll
  for(int n8=0;n8<8;n8++){
    int c0=n8*16+lk*4;
    float v[4]={a1[n8][0],a1[n8][1],a1[n8][2],a1[n8][3]};
    *(uint2*)((char*)T2+(u32)rl*256+(((u32)(2*c0))^rsw))=pk4(v);
  }
  f32x4 a2[8];
  #pragma unroll
  for(int n8=0;n8<8;n8++) a2[n8]=(f32x4){0.f,0.f,0.f,0.f};
  #pragma unroll
  for(int kc=0;kc<4;kc++){
    u32 cb=(u32)((kc*32+lk*8)*2);
    s16x8 bf=*(const s16x8*)((char*)T2+(u32)rl*256+(cb^rsw));
    #pragma unroll
    for(int n8=0;n8<8;n8++){
      s16x8 af=*(const s16x8*)(Wc1p+((n8*4+kc)<<9)+lane*8);
      a2[n8]=__builtin_amdgcn_mfma_f32_16x16x32_bf16(af,bf,a2[n8],0,0,0);
    }
  }
  #pragma unroll
  for(int n8=0;n8<8;n8++){
    int c0=n8*16+lk*4;
    float v[4]={a2[n8][0],a2[n8][1],a2[n8][2],a2[n8][3]};
    *(uint2*)((char*)T+(u32)rl*256+(((u32)(2*c0))^rsw))=pk4(v);
  }
  __syncthreads();
  uint4* out4=(uint4*)(bb+(size_t)row0*H);
  #pragma unroll
  for(int p=0;p<4;p++){
    int i=t+p*256;
    u32 row=(u32)(i>>4), colb=(u32)((i&15)*16);
    out4[i]=*(const uint4*)((const char*)T+row*256+(colb^((row&7)<<4)));
  }
}

// ==== final tail + pooling
__global__ __launch_bounds__(256) void k_tailpool(
    const u16* __restrict__ X, const u16* __restrict__ W3p, const float* __restrict__ bias3,
    const u16* __restrict__ bb,
    const u16* __restrict__ W2p, const float* __restrict__ cb2,
    const float* __restrict__ lng, const float* __restrict__ lnb,
    const int* __restrict__ validv, const u16* __restrict__ hres,
    const int* __restrict__ batch, float* __restrict__ oacc)
{
  __shared__ u16 T[64*128];
  __shared__ float pbuf[256];
  __shared__ float cntsh[2];
  int t=threadIdx.x;
  int wave=t>>6, lane=t&63, lr=lane&15, lk=lane>>4;
  int rl=wave*16+lr;
  u32 rsw=((u32)(rl&7))<<4;
  int row0=blockIdx.x*64;
  f32x4 acc[8];
  #pragma unroll
  for(int n8=0;n8<8;n8++) acc[n8]=(f32x4){0.f,0.f,0.f,0.f};
  const s16x8* B0=(const s16x8*)(X+(size_t)(row0+rl)*H);
  #pragma unroll
  for(int kc=0;kc<4;kc++){
    s16x8 bf=B0[kc*4+lk];
    #pragma unroll
    for(int n8=0;n8<8;n8++){
      s16x8 af=*(const s16x8*)(W3p+((n8*4+kc)<<9)+lane*8);
      acc[n8]=__builtin_amdgcn_mfma_f32_16x16x32_bf16(af,bf,acc[n8],0,0,0);
    }
  }
  #pragma unroll
  for(int n8=0;n8<8;n8++){
    int c0=n8*16+lk*4;
    float4 b4=*(const float4*)(bias3+c0);
    float rb[4];
    unp4(*(const uint2*)(bb+(size_t)blockIdx.x*H+c0),rb);
    float vb[4]={b4.x,b4.y,b4.z,b4.w};
    float v[4];
    #pragma unroll
    for(int j=0;j<4;j++){
      v[j]=gelu_f(acc[n8][j]+vb[j]+rb[j]);
    }
    *(uint2*)((char*)T+(u32)rl*256+(((u32)(2*c0))^rsw))=pk4(v);
  }
  f32x4 a2[8];
  #pragma unroll
  for(int n8=0;n8<8;n8++) a2[n8]=(f32x4){0.f,0.f,0.f,0.f};
  #pragma unroll
  for(int kc=0;kc<4;kc++){
    u32 cb=(u32)((kc*32+lk*8)*2);
    s16x8 bf=*(const s16x8*)((char*)T+(u32)rl*256+(cb^rsw));
    #pragma unroll
    for(int n8=0;n8<8;n8++){
      s16x8 af=*(const s16x8*)(W2p+((n8*4+kc)<<9)+lane*8);
      a2[n8]=__builtin_amdgcn_mfma_f32_16x16x32_bf16(af,bf,a2[n8],0,0,0);
    }
  }
  {
    float s=0.f,q=0.f;
    #pragma unroll
    for(int n8=0;n8<8;n8++){
      int c0=n8*16+lk*4;
      float4 b4=*(const float4*)(cb2+c0);
      float vb[4]={b4.x,b4.y,b4.z,b4.w};
      #pragma unroll
      for(int j=0;j<4;j++){
        float v=a2[n8][j]+vb[j];
        a2[n8][j]=v;
        s+=v; q+=v*v;
      }
    }
    s+=__shfl_xor(s,16); s+=__shfl_xor(s,32);
    q+=__shfl_xor(q,16); q+=__shfl_xor(q,32);
    float mu=s*(1.f/128.f);
    float rsig=rsqrtf(q*(1.f/128.f)-mu*mu+1e-5f);
    #pragma unroll
    for(int n8=0;n8<8;n8++){
      int c0=n8*16+lk*4;
      float4 g4=*(const float4*)(lng+c0);
      float4 e4=*(const float4*)(lnb+c0);
      float g[4]={g4.x,g4.y,g4.z,g4.w}, e[4]={e4.x,e4.y,e4.z,e4.w};
      float ov[4];
      #pragma unroll
      for(int j=0;j<4;j++) ov[j]=(a2[n8][j]-mu)*rsig*g[j]+e[j];
      *(uint2*)((char*)T+(u32)rl*256+(((u32)(2*c0))^rsw))=pk4(ov);
    }
  }
  pbuf[t]=0.f;
  if(t<2){
    int s=0;
    for(int j2=0;j2<32;j2++) s+=validv[row0+t*32+j2]?1:0;
    cntsh[t]=fmaxf((float)s,1.f);
  }
  __syncthreads();
  const uint4* hp=(const uint4*)(hres+(size_t)row0*H);
  float s0[8]={0,0,0,0,0,0,0,0}, s1[8]={0,0,0,0,0,0,0,0};
  #pragma unroll
  for(int p=0;p<4;p++){
    int i=t+p*256;
    u32 row=(u32)(i>>4), colb=(u32)((i&15)*16);
    int grow=row0+(int)row;
    uint4 v=*(const uint4*)((const char*)T+row*256+(colb^((row&7)<<4)));
    uint4 r=hp[i];
    float vv[8],rv[8];
    unp8(v,vv); unp8(r,rv);
    float vm=validv[grow]?1.f:0.f;
    #pragma unroll
    for(int j2=0;j2<8;j2++){
      float hh=(rv[j2]+vv[j2])*vm;
      if(p<2) s0[j2]+=hh; else s1[j2]+=hh;
    }
  }
  #pragma unroll
  for(int j2=0;j2<8;j2++){
    s0[j2]+=__shfl_xor(s0[j2],16); s0[j2]+=__shfl_xor(s0[j2],32);
    s1[j2]+=__shfl_xor(s1[j2],16); s1[j2]+=__shfl_xor(s1[j2],32);
  }
  if((lane&48)==0){
    int ch=(lane&15)*8;
    #pragma unroll
    for(int j2=0;j2<8;j2++){
      atomicAdd(&pbuf[ch+j2],s0[j2]);
      atomicAdd(&pbuf[128+ch+j2],s1[j2]);
    }
  }
  __syncthreads();
  if(t<128){
    float nodef=0.5f*(pbuf[t]/cntsh[0]+pbuf[128+t]/cntsh[1]);
    atomicAdd(&oacc[batch[blockIdx.x]*H+t],nodef);
  }
}

__global__ void k_out(const float* __restrict__ acc, const int* __restrict__ flag, void* __restrict__ out){
  int i=blockIdx.x*blockDim.x+threadIdx.x;
  if(i>=NGRAPH*H) return;
  if(*flag) ((__hip_bfloat16*)out)[i]=__float2bfloat16(acc[i]);
  else ((float*)out)[i]=acc[i];
}

extern "C" void kernel_launch(void* const* d_in, const int* in_sizes, int n_in,
                              void* d_out, int out_size, void* d_ws, size_t ws_size,
                              hipStream_t stream){
  (void)n_in; (void)out_size;
  int pofs[27]; pofs[0]=0;
  for(int i=0;i<26;i++) pofs[i+1]=pofs[i]+in_sizes[i];
  int ptot=pofs[26];

  char* wsb=(char*)d_ws;
  size_t off=0;
  auto alloc=[&](size_t bytes)->char*{ char* p=wsb+off; off+=(bytes+255)&~(size_t)255; return p; };
  int*   flag =(int*)  alloc(4);
  float* par  =(float*)alloc((size_t)ptot*4);
  u16*   h    =(u16*)  alloc((size_t)SKK*H*2);
  u16*   X    =(u16*)  alloc((size_t)SKK*H*2);
  u16*   wt   =(u16*)  alloc((size_t)28*HH*2);
  u16*   wt3  =(u16*)  alloc((size_t)HH*2);
  float* bias3=(float*)alloc(H*4);
  float* rf   =(float*)alloc((size_t)NN*H*4);
  u16*   bondb=(u16*)  alloc((size_t)16*H*2);
  u16*   hn   =(u16*)  alloc((size_t)NN*H*2);
  u16*   ag   =(u16*)  alloc((size_t)NN*H*2);
  u16*   bb   =(u16*)  alloc((size_t)NN*H*2);
  // ---- contiguous zero-init region ----
  int*   ecnt =(int*)  alloc(SS*4);
  int*   ecur =(int*)  alloc(SS*4);
  int*   gcnt =(int*)  alloc(NN*4);
  int*   gcur =(int*)  alloc(NN*4);
  float* stats=(float*)alloc(LNUM*512*4);
  float* oacc =(float*)alloc((size_t)NGRAPH*H*4);
  size_t zbytes=(size_t)SS*4+SS*4+NN*4+NN*4+LNUM*512*4+(size_t)NGRAPH*H*4;
  // ---- rest ----
  int* eoff  =(int*)alloc(SS*4);
  int* epack =(int*)alloc((size_t)EI*4);
  int* dstoff=(int*)alloc((size_t)SS*32*4);
  int* goff  =(int*)alloc(NN*4);
  int* gpack =(int*)alloc((size_t)EG*4);

  if(off>ws_size) return;

  const int* xids =(const int*)d_in[26];
  const int* iei  =(const int*)d_in[27];
  const int* iea  =(const int*)d_in[28];
  const int* gei  =(const int*)d_in[29];
  const int* gea  =(const int*)d_in[30];
  const int* nids =(const int*)d_in[31];
  const int* valid=(const int*)d_in[32];
  const int* batch=(const int*)d_in[33];

  const float* atom=par+pofs[0];
  const float* bond=par+pofs[1];
  const float* rw_w=par+pofs[2];
  const float* rw_b=par+pofs[3];
  const float* rwse=par+pofs[4];
  const float* leps=par+pofs[5];
  const float* lb1 =par+pofs[7];
  const float* lb2 =par+pofs[9];
  const float* lbng=par+pofs[10];
  const float* lbnb=par+pofs[11];
  const float* geps=par+pofs[12];
  const float* gb1 =par+pofs[14];
  const float* gb2 =par+pofs[16];
  const float* gbng=par+pofs[17];
  const float* gbnb=par+pofs[18];
  const float* cw1 =par+pofs[20];
  const float* cb1 =par+pofs[21];
  const float* cb2 =par+pofs[23];
  const float* lngp=par+pofs[24];
  const float* lnbp=par+pofs[25];

  k_sniff<<<1,256,0,stream>>>((const u16*)d_in[0], flag);
  CvtArgs ca;
  for(int i=0;i<26;i++){ ca.p[i]=d_in[i]; ca.start[i]=pofs[i]; }
  ca.start[26]=ptot;
  k_convert<<<1024,256,0,stream>>>(ca, flag, par);

  TransArgs ta;
  for(int l=0;l<LNUM;l++){
    ta.src[l*7+0]=pofs[6]+l*HH;
    ta.src[l*7+1]=pofs[8]+l*HH;
    ta.src[l*7+2]=pofs[13]+l*HH;
    ta.src[l*7+3]=pofs[15]+l*HH;
    ta.src[l*7+4]=pofs[19]+l*HH;
    ta.src[l*7+5]=pofs[20]+l*2*HH+HH;
    ta.src[l*7+6]=pofs[22]+l*HH;
  }
  k_trans<<<28,256,0,stream>>>(par, ta, wt);
  k_cvtbond<<<8,256,0,stream>>>(bond, bondb);

  (void)hipMemsetAsync(ecnt,0,zbytes,stream);

  k_hist<<<2048,256,0,stream>>>(iei+EI, EI, 5, ecnt);
  k_scan<<<1,1024,0,stream>>>(ecnt, eoff, SS);
  k_scatter_i<<<2048,256,0,stream>>>(iei, iea, eoff, ecur, epack);
  k_sortsub<<<SS,128,0,stream>>>(eoff, ecnt, epack, dstoff);
  k_hist<<<512,256,0,stream>>>(gei+EG, EG, 0, gcnt);
  k_scan<<<1,1024,0,stream>>>(gcnt, goff, NN);
  k_scatter_g<<<512,256,0,stream>>>(gei, gea, goff, gcur, gpack);

  k_rwse<<<NN,128,0,stream>>>(rwse, rw_w, rw_b, rf);

  for(int l=0;l<LNUM;l++){
    float* stl_l=stats+l*512;
    float* stg_l=stats+l*512+256;
    if(l==0){
      k_fused1<2><<<SS/2,256,0,stream>>>(h, bondb, eoff, ecnt, epack, dstoff, leps, l,
          wt+(size_t)(l*7+0)*HH, lb1+l*H, wt+(size_t)(l*7+1)*HH, lb2+l*H, X, stl_l,
          nullptr,nullptr,nullptr,nullptr,nullptr,nullptr,nullptr, valid, h,
          atom, rf, xids, nids, hn);
    } else {
      int pl=l-1;
      k_fused1<1><<<SS/2,256,0,stream>>>(h, bondb, eoff, ecnt, epack, dstoff, leps, l,
          wt+(size_t)(l*7+0)*HH, lb1+l*H, wt+(size_t)(l*7+1)*HH, lb2+l*H, X, stl_l,
          wt3, bias3, bb, wt+(size_t)(pl*7+6)*HH, cb2+pl*H,
          lngp+pl*H, lnbp+pl*H, valid, h,
          nullptr, nullptr, nullptr, nullptr, hn);
    }
    k_prepw3<<<128,128,0,stream>>>(cw1+(size_t)l*2*HH, cb1+l*H, stl_l, lbng+l*H, lbnb+l*H, wt3, bias3);
    k_node<<<NN/64,256,0,stream>>>(hn, bondb, goff, gcnt, gpack, geps, l,
        wt+(size_t)(l*7+2)*HH, gb1+l*H, wt+(size_t)(l*7+3)*HH, gb2+l*H, ag, stg_l);
    k_bcast<<<NN/64,256,0,stream>>>(hn, ag, stg_l, gbng+l*H, gbnb+l*H,
        wt+(size_t)(l*7+4)*HH, wt+(size_t)(l*7+5)*HH, bb);
  }
  {
    int l=LNUM-1;
    k_tailpool<<<SKK/64,256,0,stream>>>(X, wt3, bias3, bb,
        wt+(size_t)(l*7+6)*HH, cb2+l*H, lngp+l*H, lnbp+l*H, valid, h, batch, oacc);
  }
  k_out<<<(NGRAPH*H+255)/256,256,0,stream>>>(oacc, flag, d_out);
}

// Round 16
// 1134.405 us; speedup vs baseline: 1.0531x; 1.0467x over previous
//
#include <hip/hip_runtime.h>
#include <hip/hip_bf16.h>

#define H 128
#define HH 16384
#define LNUM 4
#define NN 4096
#define SS 8192
#define SKK 262144
#define EI 1048576
#define EG 65536
#define NGRAPH 64

typedef unsigned short u16;
typedef unsigned int u32;
typedef __attribute__((ext_vector_type(8))) short s16x8;
typedef __attribute__((ext_vector_type(4))) float f32x4;
typedef __attribute__((ext_vector_type(8))) _Float16 f16x8;

__device__ __forceinline__ float b2f(u32 u){ return __uint_as_float(u<<16); }
__device__ __forceinline__ u16 f2b(float f){
  union { __hip_bfloat16 b; u16 u; } x;
  x.b=__float2bfloat16(f);
  return x.u;
}
__device__ __forceinline__ void unp8(uint4 v, float* f){
  f[0]=b2f(v.x&0xFFFF); f[1]=b2f(v.x>>16);
  f[2]=b2f(v.y&0xFFFF); f[3]=b2f(v.y>>16);
  f[4]=b2f(v.z&0xFFFF); f[5]=b2f(v.z>>16);
  f[6]=b2f(v.w&0xFFFF); f[7]=b2f(v.w>>16);
}
__device__ __forceinline__ void unp4(uint2 v, float* f){
  f[0]=b2f(v.x&0xFFFF); f[1]=b2f(v.x>>16);
  f[2]=b2f(v.y&0xFFFF); f[3]=b2f(v.y>>16);
}
__device__ __forceinline__ uint4 pk8(const float* f){
  uint4 r;
  r.x=(u32)f2b(f[0])|((u32)f2b(f[1])<<16);
  r.y=(u32)f2b(f[2])|((u32)f2b(f[3])<<16);
  r.z=(u32)f2b(f[4])|((u32)f2b(f[5])<<16);
  r.w=(u32)f2b(f[6])|((u32)f2b(f[7])<<16);
  return r;
}
__device__ __forceinline__ uint2 pk4(const float* f){
  uint2 r;
  r.x=(u32)f2b(f[0])|((u32)f2b(f[1])<<16);
  r.y=(u32)f2b(f[2])|((u32)f2b(f[3])<<16);
  return r;
}
// tanh-form gelu
__device__ __forceinline__ float gelu_f(float x){
  float u=x*(0.7978845608f+0.0356774081f*x*x);
  float ex=__expf(fminf(2.f*u,80.f));
  return x*(ex/(ex+1.f));
}

struct CvtArgs {
  const void* p[26];
  int start[27];
};
struct TransArgs { int src[28]; };

// ---- dtype sniff
__global__ void k_sniff(const u16* __restrict__ a, int* __restrict__ flag){
  __shared__ int cnt;
  if(threadIdx.x==0) cnt=0;
  __syncthreads();
  int big=0;
  for(int i=threadIdx.x;i<2048;i+=256){
    int e=(a[i]>>7)&0xFF;
    if(e>=127) big++;
  }
  atomicAdd(&cnt,big);
  __syncthreads();
  if(threadIdx.x==0) *flag=(cnt<16)?1:0;
}

__global__ void k_convert(CvtArgs args, const int* __restrict__ flag, float* __restrict__ dst){
  int fl=*flag;
  int total=args.start[26];
  for(int i=blockIdx.x*blockDim.x+threadIdx.x;i<total;i+=gridDim.x*blockDim.x){
    int a=0;
    while(args.start[a+1]<=i) a++;
    int j=i-args.start[a];
    float v;
    if(fl) v=b2f(((const u16*)args.p[a])[j]);
    else   v=((const float*)args.p[a])[j];
    dst[i]=v;
  }
}

// ---- static weights: f32 [K][N] -> bf16 fragment-major packed
__global__ __launch_bounds__(256) void k_trans(const float* __restrict__ par, TransArgs ta, u16* __restrict__ wt){
  const float* s=par+ta.src[blockIdx.x];
  u16* d=wt+(size_t)blockIdx.x*HH;
  for(int i=threadIdx.x;i<HH;i+=256){
    int j=i&7, lane=(i>>3)&63, fc=i>>9;
    int n=fc>>2, kc=fc&3, lr=lane&15, lk=lane>>4;
    int outc=n*16+lr, k=kc*32+lk*8+j;
    d[i]=f2b(s[(size_t)k*H+outc]);
  }
}

// ---- bond emb f32 -> bf16
__global__ void k_cvtbond(const float* __restrict__ b, u16* __restrict__ bb){
  int i=blockIdx.x*blockDim.x+threadIdx.x;
  if(i<16*H) bb[i]=f2b(b[i]);
}

// ---- fold local-BN affine into cw1_top, packed output
__global__ __launch_bounds__(128) void k_prepw3(const float* __restrict__ w, const float* __restrict__ cb1,
                        const float* __restrict__ stl, const float* __restrict__ gl, const float* __restrict__ bl,
                        u16* __restrict__ wt3p, float* __restrict__ bias3){
  __shared__ float red[128];
  int c=blockIdx.x, k=threadIdx.x;
  float mu=stl[k]*(1.f/262144.f);
  float var=stl[128+k]*(1.f/262144.f)-mu*mu;
  float s=gl[k]*rsqrtf(var+1e-5f);
  float tt=bl[k]-mu*s;
  float wv=w[(size_t)k*H+c];
  int idx=(((c>>4)*4+(k>>5))*64+((k>>3)&3)*16+(c&15))*8+(k&7);
  wt3p[idx]=f2b(s*wv);
  red[k]=tt*wv;
  __syncthreads();
  for(int d=64;d>0;d>>=1){ if(k<d) red[k]+=red[k+d]; __syncthreads(); }
  if(k==0) bias3[c]=cb1[c]+red[0];
}

// ---- edge bucketing
__global__ void k_hist(const int* __restrict__ idx, int n, int shift, int* __restrict__ cnt){
  for(int i=blockIdx.x*blockDim.x+threadIdx.x;i<n;i+=gridDim.x*blockDim.x)
    atomicAdd(&cnt[idx[i]>>shift],1);
}

__global__ void k_scan(const int* __restrict__ cnt, int* __restrict__ off, int nbins){
  __shared__ int ts[1024];
  int t=threadIdx.x;
  int per=nbins>>10;
  int base=t*per;
  int s=0;
  for(int j=0;j<per;j++) s+=cnt[base+j];
  ts[t]=s;
  __syncthreads();
  for(int d=1;d<1024;d<<=1){
    int v=(t>=d)?ts[t-d]:0;
    __syncthreads();
    ts[t]+=v;
    __syncthreads();
  }
  int ex=(t==0)?0:ts[t-1];
  for(int j=0;j<per;j++){ off[base+j]=ex; ex+=cnt[base+j]; }
}

__global__ void k_scatter_i(const int* __restrict__ ei, const int* __restrict__ ea,
                            const int* __restrict__ off, int* __restrict__ cur, int* __restrict__ pack){
  for(int i=blockIdx.x*blockDim.x+threadIdx.x;i<EI;i+=gridDim.x*blockDim.x){
    int s=ei[i], d=ei[EI+i];
    int sub=d>>5;
    int pos=off[sub]+atomicAdd(&cur[sub],1);
    pack[pos]=((s&31)<<9)|((d&31)<<4)|(ea[i]&15);
  }
}

// ---- sort each subgraph's edges by dst-lane; persist per-dst segment starts
__global__ __launch_bounds__(128) void k_sortsub(const int* __restrict__ eoff, const int* __restrict__ ecnt,
                                                 int* __restrict__ epack, int* __restrict__ dstoff){
  __shared__ int ein[512];
  __shared__ int eout[512];
  __shared__ int bcnt[32];
  __shared__ int bpos[32];
  int sub=blockIdx.x, t=threadIdx.x;
  int o=eoff[sub];
  int n=ecnt[sub]; if(n>512) n=512;
  for(int i=t;i<n;i+=128) ein[i]=epack[o+i];
  if(t<32) bcnt[t]=0;
  __syncthreads();
  for(int i=t;i<n;i+=128) atomicAdd(&bcnt[(ein[i]>>4)&31],1);
  __syncthreads();
  if(t==0){
    int s=0;
    for(int b=0;b<32;b++){ bpos[b]=s; s+=bcnt[b]; }
  }
  __syncthreads();
  if(t<32) dstoff[sub*32+t]=bpos[t];
  __syncthreads();
  for(int i=t;i<n;i+=128){
    int p=ein[i];
    int pos=atomicAdd(&bpos[(p>>4)&31],1);
    eout[pos]=p;
  }
  __syncthreads();
  for(int i=t;i<n;i+=128) epack[o+i]=eout[i];
}

__global__ void k_scatter_g(const int* __restrict__ ei, const int* __restrict__ ea,
                            const int* __restrict__ off, int* __restrict__ cur, int* __restrict__ pack){
  for(int i=blockIdx.x*blockDim.x+threadIdx.x;i<EG;i+=gridDim.x*blockDim.x){
    int s=ei[i], d=ei[EG+i];
    int pos=off[d]+atomicAdd(&cur[d],1);
    pack[pos]=(s<<4)|(ea[i]&15);
  }
}

// ---- rf = relu(rwse @ rwse_w + rwse_b)
__global__ __launch_bounds__(128) void k_rwse(const float* __restrict__ rwse, const float* __restrict__ w,
                      const float* __restrict__ b, float* __restrict__ rf){
  __shared__ float ws[16*128];
  __shared__ float rv[16];
  int n=blockIdx.x, c=threadIdx.x;
  for(int i=c;i<2048;i+=128) ws[i]=w[i];
  if(c<16) rv[c]=rwse[n*16+c];
  __syncthreads();
  float acc=b[c];
  for(int j=0;j<16;j++) acc=fmaf(rv[j],ws[j*128+c],acc);
  rf[(size_t)n*H+c]=fmaxf(acc,0.f);
}

// ==== FUSED mega-kernel. MODE 1: prev-layer tail first. MODE 2: build h0 in-block.
template<int MODE>
__global__ __launch_bounds__(256,4) void k_fused1(
    const u16* __restrict__ h, const u16* __restrict__ beb,
    const int* __restrict__ eoff, const int* __restrict__ ecnt, const int* __restrict__ epack,
    const int* __restrict__ dstoff,
    const float* __restrict__ epsp, int layer,
    const u16* __restrict__ W1p, const float* __restrict__ b1,
    const u16* __restrict__ W2p, const float* __restrict__ b2,
    u16* __restrict__ Xg, float* __restrict__ stats,
    const u16* __restrict__ W3p, const float* __restrict__ bias3,
    const u16* __restrict__ bbv,
    const u16* __restrict__ Wc2p, const float* __restrict__ cb2,
    const float* __restrict__ lng, const float* __restrict__ lnb,
    const int* __restrict__ validv, u16* __restrict__ hio,
    const float* __restrict__ atomp, const float* __restrict__ rfp,
    const int* __restrict__ xids, const int* __restrict__ nids,
    u16* __restrict__ hnOut)
{
  __shared__ u16 hs[64*128];      // bf16 h; converted in place to f16 for agg; later MLP intermediate
  __shared__ u16 agx[64*128];
  __shared__ u16 bes[16*128];     // f16 bond emb (agg only)
  __shared__ u16 epku[2][512];
  __shared__ int doff[2][32];
  float* sst=(float*)&epku[0][0];

  int t=threadIdx.x;
  int grp=t>>7, c=t&127;
  size_t hbase=(size_t)blockIdx.x*64*H;
  int wave=t>>6, lane=t&63, lr=lane&15, lk=lane>>4;
  int rl=wave*16+lr;
  u32 rsw=((u32)(rl&7))<<4;
  int row0=blockIdx.x*64;

  {
    u32 row=(u32)(t>>4), colb=(u32)((t&15)*16);
    uint4 bv=((const uint4*)beb)[t];
    float bf[8];
    unp8(bv,bf);
    f16x8 bh;
    #pragma unroll
    for(int j=0;j<8;j++) bh[j]=(_Float16)bf[j];
    *(f16x8*)((char*)bes+row*256+(colb^((row&7)<<4)))=bh;
  }
  int sub=blockIdx.x*2+grp;
  int n=min(ecnt[sub],512);
  int o=eoff[sub];
  if(c<32) doff[grp][c]=dstoff[sub*32+c];
  for(int i=c;i<n;i+=128) epku[grp][i]=(u16)epack[o+i];

  if(MODE==1){
    f32x4 a1t[8];
    #pragma unroll
    for(int n8=0;n8<8;n8++) a1t[n8]=(f32x4){0.f,0.f,0.f,0.f};
    const s16x8* B0=(const s16x8*)(Xg+(size_t)(row0+rl)*H);
    #pragma unroll
    for(int kc=0;kc<4;kc++){
      s16x8 bf=B0[kc*4+lk];
      #pragma unroll
      for(int n8=0;n8<8;n8++){
        s16x8 af=*(const s16x8*)(W3p+((n8*4+kc)<<9)+lane*8);
        a1t[n8]=__builtin_amdgcn_mfma_f32_16x16x32_bf16(af,bf,a1t[n8],0,0,0);
      }
    }
    #pragma unroll
    for(int n8=0;n8<8;n8++){
      int c0=n8*16+lk*4;
      float4 b4=*(const float4*)(bias3+c0);
      float rb[4];
      unp4(*(const uint2*)(bbv+(size_t)blockIdx.x*H+c0),rb);
      float vb[4]={b4.x,b4.y,b4.z,b4.w};
      float v[4];
      #pragma unroll
      for(int j=0;j<4;j++){
        v[j]=gelu_f(a1t[n8][j]+vb[j]+rb[j]);
      }
      *(uint2*)((char*)agx+(u32)rl*256+(((u32)(2*c0))^rsw))=pk4(v);
    }
    f32x4 a2t[8];
    #pragma unroll
    for(int n8=0;n8<8;n8++) a2t[n8]=(f32x4){0.f,0.f,0.f,0.f};
    #pragma unroll
    for(int kc=0;kc<4;kc++){
      u32 cb=(u32)((kc*32+lk*8)*2);
      s16x8 bf=*(const s16x8*)((char*)agx+(u32)rl*256+(cb^rsw));
      #pragma unroll
      for(int n8=0;n8<8;n8++){
        s16x8 af=*(const s16x8*)(Wc2p+((n8*4+kc)<<9)+lane*8);
        a2t[n8]=__builtin_amdgcn_mfma_f32_16x16x32_bf16(af,bf,a2t[n8],0,0,0);
      }
    }
    {
      float s=0.f,q=0.f;
      #pragma unroll
      for(int n8=0;n8<8;n8++){
        int c0=n8*16+lk*4;
        float4 b4=*(const float4*)(cb2+c0);
        float vb[4]={b4.x,b4.y,b4.z,b4.w};
        #pragma unroll
        for(int j=0;j<4;j++){
          float v=a2t[n8][j]+vb[j];
          a2t[n8][j]=v;
          s+=v; q+=v*v;
        }
      }
      s+=__shfl_xor(s,16); s+=__shfl_xor(s,32);
      q+=__shfl_xor(q,16); q+=__shfl_xor(q,32);
      float mu=s*(1.f/128.f);
      float rsig=rsqrtf(q*(1.f/128.f)-mu*mu+1e-5f);
      #pragma unroll
      for(int n8=0;n8<8;n8++){
        int c0=n8*16+lk*4;
        float4 g4=*(const float4*)(lng+c0);
        float4 e4=*(const float4*)(lnb+c0);
        float g[4]={g4.x,g4.y,g4.z,g4.w}, e[4]={e4.x,e4.y,e4.z,e4.w};
        float ov[4];
        #pragma unroll
        for(int j=0;j<4;j++) ov[j]=(a2t[n8][j]-mu)*rsig*g[j]+e[j];
        *(uint2*)((char*)agx+(u32)rl*256+(((u32)(2*c0))^rsw))=pk4(ov);
      }
    }
    __syncthreads();
    uint4* hp=(uint4*)(hio+hbase);
    #pragma unroll
    for(int p=0;p<4;p++){
      int i=t+p*256;
      u32 row=(u32)(i>>4), colb=(u32)((i&15)*16);
      int grow=row0+(int)row;
      uint4 v=*(const uint4*)((const char*)agx+row*256+(colb^((row&7)<<4)));
      uint4 r=hp[i];
      float vv[8],rv[8],o8[8];
      unp8(v,vv); unp8(r,rv);
      float vm=validv[grow]?1.f:0.f;
      #pragma unroll
      for(int j=0;j<8;j++) o8[j]=(rv[j]+vv[j])*vm;
      uint4 pk=pk8(o8);
      hp[i]=pk;
      *(uint4*)((char*)hs+row*256+(colb^((row&7)<<4)))=pk;
    }
  } else {
    int r=t>>2, q=t&3;
    int grow=row0+r;
    float vm=validv[grow]?1.f:0.f;
    const float4* ap=(const float4*)(atomp+(size_t)xids[grow]*H)+q*8;
    const float4* bp=(const float4*)(rfp+(size_t)nids[grow]*H)+q*8;
    u32 rowsw=((u32)(r&7))<<4;
    uint4* hgp=(uint4*)(hio+hbase);
    #pragma unroll
    for(int k=0;k<4;k++){
      float4 a0=ap[k*2], a1=ap[k*2+1], b0=bp[k*2], b1=bp[k*2+1];
      float f[8]={(a0.x+b0.x)*vm,(a0.y+b0.y)*vm,(a0.z+b0.z)*vm,(a0.w+b0.w)*vm,
                  (a1.x+b1.x)*vm,(a1.y+b1.y)*vm,(a1.z+b1.z)*vm,(a1.w+b1.w)*vm};
      uint4 pk=pk8(f);
      u32 cb=(u32)(q*64+k*16);
      *(uint4*)((char*)hs+(u32)r*256+(cb^rowsw))=pk;
      hgp[r*16+q*4+k]=pk;
    }
  }
  __syncthreads();

  if(t<16){
    uint4 aR=*(const uint4*)((const char*)hs+(u32)t*16);
    uint4 bR=*(const uint4*)((const char*)hs+32*256+(u32)t*16);
    float fa[8],fb[8],fo[8];
    unp8(aR,fa); unp8(bR,fb);
    #pragma unroll
    for(int j=0;j<8;j++) fo[j]=0.5f*(fa[j]+fb[j]);
    ((uint4*)(hnOut+(size_t)blockIdx.x*H))[t]=pk8(fo);
  }
  // init agx = (1+eps)*h (bf16) AND convert hs in place bf16 -> f16 for the agg
  {
    float ep=1.f+epsp[layer];
    #pragma unroll
    for(int p=0;p<4;p++){
      int i=t+p*256;
      u32 row=(u32)(i>>4), colb=(u32)((i&15)*16);
      u32 off=row*256+(colb^((row&7)<<4));
      float hf[8],o8[8];
      unp8(*(const uint4*)((const char*)hs+off),hf);
      #pragma unroll
      for(int j=0;j<8;j++) o8[j]=ep*hf[j];
      *(uint4*)((char*)agx+off)=pk8(o8);
      f16x8 h16;
      #pragma unroll
      for(int j=0;j<8;j++) h16[j]=(_Float16)hf[j];
      *(f16x8*)((char*)hs+off)=h16;
    }
  }
  __syncthreads();

  // ---- aggregation in packed f16: thread owns dsts [4*slot,4*slot+4), 2-deep pipeline
  {
    int slot=c>>4, chg=c&15;
    u32 cbyte=(u32)chg*16;
    int d0=slot*4;
    int s0=doff[grp][d0];
    int send=(d0+3==31)?n:doff[grp][d0+4];
    const u16* ep_=&epku[grp][0];
    auto LDP=[&](int p, f16x8& hv, f16x8& bv){
      u32 srow=(u32)(grp*32+(p>>9));
      u32 erow=(u32)(p&15);
      hv=*(const f16x8*)((const char*)hs+srow*256+(cbyte^((srow&7)<<4)));
      bv=*(const f16x8*)((const char*)bes+erow*256+(cbyte^((erow&7)<<4)));
    };
    auto FLUSH=[&](int cur, f16x8 a){
      u32 drow=(u32)(grp*32+cur);
      u32 aoff=drow*256+(cbyte^((drow&7)<<4));
      float of[8];
      unp8(*(const uint4*)((const char*)agx+aoff),of);
      #pragma unroll
      for(int q=0;q<8;q++) of[q]+=(float)a[q];
      *(uint4*)((char*)agx+aoff)=pk8(of);
    };
    f16x8 acc;
    #pragma unroll
    for(int q=0;q<8;q++) acc[q]=(_Float16)0;
    int cur=-1;
    f16x8 hvA,bvA,hvB,bvB;
    #pragma unroll
    for(int q=0;q<8;q++){ hvA[q]=(_Float16)0; bvA[q]=(_Float16)0; hvB[q]=(_Float16)0; bvB[q]=(_Float16)0; }
    int pA=0,pB=0;
    if(s0<send){ pA=ep_[s0]; LDP(pA,hvA,bvA); }
    if(s0+1<send){ pB=ep_[s0+1]; LDP(pB,hvB,bvB); }
    for(int j=s0;j<send;){
      {
        f16x8 m=hvA+bvA;
        int pc=pA;
        if(j+2<send){ pA=ep_[j+2]; LDP(pA,hvA,bvA); }
        int dl=(pc>>4)&31;
        if(dl!=cur){
          if(cur>=0) FLUSH(cur,acc);
          #pragma unroll
          for(int q=0;q<8;q++) acc[q]=(_Float16)0;
          cur=dl;
        }
        #pragma unroll
        for(int q=0;q<8;q++){ _Float16 z=(_Float16)0; m[q]=(m[q]>z)?m[q]:z; }
        acc+=m;
      }
      j++;
      if(j>=send) break;
      {
        f16x8 m=hvB+bvB;
        int pc=pB;
        if(j+2<send){ pB=ep_[j+2]; LDP(pB,hvB,bvB); }
        int dl=(pc>>4)&31;
        if(dl!=cur){
          if(cur>=0) FLUSH(cur,acc);
          #pragma unroll
          for(int q=0;q<8;q++) acc[q]=(_Float16)0;
          cur=dl;
        }
        #pragma unroll
        for(int q=0;q<8;q++){ _Float16 z=(_Float16)0; m[q]=(m[q]>z)?m[q]:z; }
        acc+=m;
      }
      j++;
    }
    if(cur>=0) FLUSH(cur,acc);
  }
  __syncthreads();
  sst[t]=0.f;
  __syncthreads();

  f32x4 a1[8];
  #pragma unroll
  for(int n8=0;n8<8;n8++) a1[n8]=(f32x4){0.f,0.f,0.f,0.f};
  #pragma unroll
  for(int kc=0;kc<4;kc++){
    u32 cb=(u32)((kc*32+lk*8)*2);
    s16x8 bf=*(const s16x8*)((char*)agx+(u32)rl*256+(cb^rsw));
    #pragma unroll
    for(int n8=0;n8<8;n8++){
      s16x8 af=*(const s16x8*)(W1p+((n8*4+kc)<<9)+lane*8);
      a1[n8]=__builtin_amdgcn_mfma_f32_16x16x32_bf16(af,bf,a1[n8],0,0,0);
    }
  }
  #pragma unroll
  for(int n8=0;n8<8;n8++){
    int c0=n8*16+lk*4;
    float4 b4=*(const float4*)(b1+c0);
    float v[4]={fmaxf(a1[n8][0]+b4.x,0.f),fmaxf(a1[n8][1]+b4.y,0.f),
                fmaxf(a1[n8][2]+b4.z,0.f),fmaxf(a1[n8][3]+b4.w,0.f)};
    *(uint2*)((char*)hs+(u32)rl*256+(((u32)(2*c0))^rsw))=pk4(v);
  }
  f32x4 a2[8];
  #pragma unroll
  for(int n8=0;n8<8;n8++) a2[n8]=(f32x4){0.f,0.f,0.f,0.f};
  #pragma unroll
  for(int kc=0;kc<4;kc++){
    u32 cb=(u32)((kc*32+lk*8)*2);
    s16x8 bf=*(const s16x8*)((char*)hs+(u32)rl*256+(cb^rsw));
    #pragma unroll
    for(int n8=0;n8<8;n8++){
      s16x8 af=*(const s16x8*)(W2p+((n8*4+kc)<<9)+lane*8);
      a2[n8]=__builtin_amdgcn_mfma_f32_16x16x32_bf16(af,bf,a2[n8],0,0,0);
    }
  }
  // epilogue: relu(+b2) -> agx + stats (round-13 proven form)
  #pragma unroll
  for(int n8=0;n8<8;n8++){
    int c0=n8*16+lk*4;
    float4 b4=*(const float4*)(b2+c0);
    float v[4]={fmaxf(a2[n8][0]+b4.x,0.f),fmaxf(a2[n8][1]+b4.y,0.f),
                fmaxf(a2[n8][2]+b4.z,0.f),fmaxf(a2[n8][3]+b4.w,0.f)};
    *(uint2*)((char*)agx+(u32)rl*256+(((u32)(2*c0))^rsw))=pk4(v);
    float s[4],q[4];
    #pragma unroll
    for(int j2=0;j2<4;j2++){ s[j2]=v[j2]; q[j2]=v[j2]*v[j2]; }
    #pragma unroll
    for(int j2=0;j2<4;j2++){
      #pragma unroll
      for(int d=1;d<16;d<<=1){
        s[j2]+=__shfl_xor(s[j2],d);
        q[j2]+=__shfl_xor(q[j2],d);
      }
    }
    if(lr==0){
      #pragma unroll
      for(int j2=0;j2<4;j2++){
        atomicAdd(&sst[c0+j2],s[j2]);
        atomicAdd(&sst[128+c0+j2],q[j2]);
      }
    }
  }
  __syncthreads();
  uint4* out4=(uint4*)(Xg+hbase);
  #pragma unroll
  for(int p=0;p<4;p++){
    int i=t+p*256;
    u32 row=(u32)(i>>4), colb=(u32)((i&15)*16);
    out4[i]=*(const uint4*)((const char*)agx+row*256+(colb^((row&7)<<4)));
  }
  atomicAdd(&stats[t],sst[t]);
}

// ==== fused node path: global GINE agg (64 nodes) + 2-GEMM MLP + stats
__global__ __launch_bounds__(256) void k_node(
    const u16* __restrict__ hn, const u16* __restrict__ beb,
    const int* __restrict__ goff, const int* __restrict__ gcnt, const int* __restrict__ gpack,
    const float* __restrict__ epsp, int layer,
    const u16* __restrict__ W1p, const float* __restrict__ b1,
    const u16* __restrict__ W2p, const float* __restrict__ b2,
    u16* __restrict__ ag, float* __restrict__ stats)
{
  __shared__ u16 T[64*128];
  __shared__ u16 T2[64*128];
  __shared__ u16 bes[16*128];
  __shared__ float sst[256];
  int t=threadIdx.x;
  sst[t]=0.f;
  ((uint4*)bes)[t]=((const uint4*)beb)[t];
  __syncthreads();
  int node4=t>>2, q=t&3;
  int gnode=blockIdx.x*64+node4;
  float acc[32];
  float ep=1.f+epsp[layer];
  {
    const uint4* hrow=(const uint4*)(hn+(size_t)gnode*H+q*32);
    #pragma unroll
    for(int v=0;v<4;v++){
      float tmp[8];
      unp8(hrow[v],tmp);
      #pragma unroll
      for(int j=0;j<8;j++) acc[v*8+j]=ep*tmp[j];
    }
  }
  int o=goff[gnode], e=o+gcnt[gnode];
  for(;o<e;o++){
    int p=gpack[o];
    const uint4* srow=(const uint4*)(hn+(size_t)(p>>4)*H+q*32);
    const uint4* brow=(const uint4*)(bes+(p&15)*128+q*32);
    #pragma unroll
    for(int v=0;v<4;v++){
      float tmp[8],bf8[8];
      unp8(srow[v],tmp); unp8(brow[v],bf8);
      #pragma unroll
      for(int j=0;j<8;j++) acc[v*8+j]+=fmaxf(tmp[j]+bf8[j],0.f);
    }
  }
  {
    u32 rs=((u32)(node4&7))<<4;
    #pragma unroll
    for(int v=0;v<4;v++){
      u32 cb=(u32)((q*32+v*8)*2);
      *(uint4*)((char*)T+(u32)node4*256+(cb^rs))=pk8(&acc[v*8]);
    }
  }
  __syncthreads();
  int wave=t>>6, lane=t&63, lr=lane&15, lk=lane>>4;
  int rl=wave*16+lr;
  u32 rsw=((u32)(rl&7))<<4;
  int row0=blockIdx.x*64;
  f32x4 a1[8];
  #pragma unroll
  for(int n8=0;n8<8;n8++) a1[n8]=(f32x4){0.f,0.f,0.f,0.f};
  #pragma unroll
  for(int kc=0;kc<4;kc++){
    u32 cb=(u32)((kc*32+lk*8)*2);
    s16x8 bf=*(const s16x8*)((char*)T+(u32)rl*256+(cb^rsw));
    #pragma unroll
    for(int n8=0;n8<8;n8++){
      s16x8 af=*(const s16x8*)(W1p+((n8*4+kc)<<9)+lane*8);
      a1[n8]=__builtin_amdgcn_mfma_f32_16x16x32_bf16(af,bf,a1[n8],0,0,0);
    }
  }
  #pragma unroll
  for(int n8=0;n8<8;n8++){
    int c0=n8*16+lk*4;
    float4 b4=*(const float4*)(b1+c0);
    float v[4]={fmaxf(a1[n8][0]+b4.x,0.f),fmaxf(a1[n8][1]+b4.y,0.f),
                fmaxf(a1[n8][2]+b4.z,0.f),fmaxf(a1[n8][3]+b4.w,0.f)};
    *(uint2*)((char*)T2+(u32)rl*256+(((u32)(2*c0))^rsw))=pk4(v);
  }
  f32x4 a2[8];
  #pragma unroll
  for(int n8=0;n8<8;n8++) a2[n8]=(f32x4){0.f,0.f,0.f,0.f};
  #pragma unroll
  for(int kc=0;kc<4;kc++){
    u32 cb=(u32)((kc*32+lk*8)*2);
    s16x8 bf=*(const s16x8*)((char*)T2+(u32)rl*256+(cb^rsw));
    #pragma unroll
    for(int n8=0;n8<8;n8++){
      s16x8 af=*(const s16x8*)(W2p+((n8*4+kc)<<9)+lane*8);
      a2[n8]=__builtin_amdgcn_mfma_f32_16x16x32_bf16(af,bf,a2[n8],0,0,0);
    }
  }
  #pragma unroll
  for(int n8=0;n8<8;n8++){
    int c0=n8*16+lk*4;
    float4 b4=*(const float4*)(b2+c0);
    float v[4]={fmaxf(a2[n8][0]+b4.x,0.f),fmaxf(a2[n8][1]+b4.y,0.f),
                fmaxf(a2[n8][2]+b4.z,0.f),fmaxf(a2[n8][3]+b4.w,0.f)};
    *(uint2*)((char*)T+(u32)rl*256+(((u32)(2*c0))^rsw))=pk4(v);
    float s[4],qq[4];
    #pragma unroll
    for(int j=0;j<4;j++){ s[j]=v[j]; qq[j]=v[j]*v[j]; }
    #pragma unroll
    for(int j=0;j<4;j++){
      #pragma unroll
      for(int d=1;d<16;d<<=1){
        s[j]+=__shfl_xor(s[j],d);
        qq[j]+=__shfl_xor(qq[j],d);
      }
    }
    if(lr==0){
      #pragma unroll
      for(int j=0;j<4;j++){
        atomicAdd(&sst[c0+j],s[j]);
        atomicAdd(&sst[128+c0+j],qq[j]);
      }
    }
  }
  __syncthreads();
  uint4* out4=(uint4*)(ag+(size_t)row0*H);
  #pragma unroll
  for(int p=0;p<4;p++){
    int i=t+p*256;
    u32 row=(u32)(i>>4), colb=(u32)((i&15)*16);
    out4[i]=*(const uint4*)((const char*)T+row*256+(colb^((row&7)<<4)));
  }
  atomicAdd(&stats[t],sst[t]);
}

// ==== fused node broadcast: bb = ((hn + BN(ag)) @ bcw) @ cw1_bot
__global__ __launch_bounds__(256) void k_bcast(
    const u16* __restrict__ hn, const u16* __restrict__ ag,
    const float* __restrict__ stg, const float* __restrict__ gg, const float* __restrict__ bg,
    const u16* __restrict__ Wbcp, const u16* __restrict__ Wc1p,
    u16* __restrict__ bb)
{
  __shared__ u16 T[64*128];
  __shared__ u16 T2[64*128];
  __shared__ float ssh[128], tsh[128];
  int t=threadIdx.x;
  int row0=blockIdx.x*64;
  if(t<128){
    float mu=stg[t]*(1.f/4096.f);
    float var=stg[128+t]*(1.f/4096.f)-mu*mu;
    float s=gg[t]*rsqrtf(var+1e-5f);
    ssh[t]=s; tsh[t]=bg[t]-mu*s;
  }
  __syncthreads();
  #pragma unroll
  for(int i0=0;i0<4;i0++){
    int i=t+i0*256;
    u32 row=(u32)(i>>4);
    int cb8=(i&15)*8;
    float hv[8],av[8],o8[8];
    unp8(((const uint4*)(hn+(size_t)row0*H))[i],hv);
    unp8(((const uint4*)(ag+(size_t)row0*H))[i],av);
    #pragma unroll
    for(int j=0;j<8;j++) o8[j]=hv[j]+fmaf(av[j],ssh[cb8+j],tsh[cb8+j]);
    *(uint4*)((char*)T+row*256+(((u32)(cb8*2))^((row&7)<<4)))=pk8(o8);
  }
  __syncthreads();
  int wave=t>>6, lane=t&63, lr=lane&15, lk=lane>>4;
  int rl=wave*16+lr;
  u32 rsw=((u32)(rl&7))<<4;
  f32x4 a1[8];
  #pragma unroll
  for(int n8=0;n8<8;n8++) a1[n8]=(f32x4){0.f,0.f,0.f,0.f};
  #pragma unroll
  for(int kc=0;kc<4;kc++){
    u32 cb=(u32)((kc*32+lk*8)*2);
    s16x8 bf=*(const s16x8*)((char*)T+(u32)rl*256+(cb^rsw));
    #pragma unroll
    for(int n8=0;n8<8;n8++){
      s16x8 af=*(const s16x8*)(Wbcp+((n8*4+kc)<<9)+lane*8);
      a1[n8]=__builtin_amdgcn_mfma_f32_16x16x32_bf16(af,bf,a1[n8],0,0,0);
    }
  }
  #pragma unroll
  for(int n8=0;n8<8;n8++){
    int c0=n8*16+lk*4;
    float v[4]={a1[n8][0],a1[n8][1],a1[n8][2],a1[n8][3]};
    *(uint2*)((char*)T2+(u32)rl*256+(((u32)(2*c0))^rsw))=pk4(v);
  }
  f32x4 a2[8];
  #pragma unroll
  for(int n8=0;n8<8;n8++) a2[n8]=(f32x4){0.f,0.f,0.f,0.f};
  #pragma unroll
  for(int kc=0;kc<4;kc++){
    u32 cb=(u32)((kc*32+lk*8)*2);
    s16x8 bf=*(const s16x8*)((char*)T2+(u32)rl*256+(cb^rsw));
    #pragma unroll
    for(int n8=0;n8<8;n8++){
      s16x8 af=*(const s16x8*)(Wc1p+((n8*4+kc)<<9)+lane*8);
      a2[n8]=__builtin_amdgcn_mfma_f32_16x16x32_bf16(af,bf,a2[n8],0,0,0);
    }
  }
  #pragma unroll
  for(int n8=0;n8<8;n8++){
    int c0=n8*16+lk*4;
    float v[4]={a2[n8][0],a2[n8][1],a2[n8][2],a2[n8][3]};
    *(uint2*)((char*)T+(u32)rl*256+(((u32)(2*c0))^rsw))=pk4(v);
  }
  __syncthreads();
  uint4* out4=(uint4*)(bb+(size_t)row0*H);
  #pragma unroll
  for(int p=0;p<4;p++){
    int i=t+p*256;
    u32 row=(u32)(i>>4), colb=(u32)((i&15)*16);
    out4[i]=*(const uint4*)((const char*)T+row*256+(colb^((row&7)<<4)));
  }
}

// ==== final tail + pooling
__global__ __launch_bounds__(256) void k_tailpool(
    const u16* __restrict__ X, const u16* __restrict__ W3p, const float* __restrict__ bias3,
    const u16* __restrict__ bb,
    const u16* __restrict__ W2p, const float* __restrict__ cb2,
    const float* __restrict__ lng, const float* __restrict__ lnb,
    const int* __restrict__ validv, const u16* __restrict__ hres,
    const int* __restrict__ batch, float* __restrict__ oacc)
{
  __shared__ u16 T[64*128];
  __shared__ float pbuf[256];
  __shared__ float cntsh[2];
  int t=threadIdx.x;
  int wave=t>>6, lane=t&63, lr=lane&15, lk=lane>>4;
  int rl=wave*16+lr;
  u32 rsw=((u32)(rl&7))<<4;
  int row0=blockIdx.x*64;
  f32x4 acc[8];
  #pragma unroll
  for(int n8=0;n8<8;n8++) acc[n8]=(f32x4){0.f,0.f,0.f,0.f};
  const s16x8* B0=(const s16x8*)(X+(size_t)(row0+rl)*H);
  #pragma unroll
  for(int kc=0;kc<4;kc++){
    s16x8 bf=B0[kc*4+lk];
    #pragma unroll
    for(int n8=0;n8<8;n8++){
      s16x8 af=*(const s16x8*)(W3p+((n8*4+kc)<<9)+lane*8);
      acc[n8]=__builtin_amdgcn_mfma_f32_16x16x32_bf16(af,bf,acc[n8],0,0,0);
    }
  }
  #pragma unroll
  for(int n8=0;n8<8;n8++){
    int c0=n8*16+lk*4;
    float4 b4=*(const float4*)(bias3+c0);
    float rb[4];
    unp4(*(const uint2*)(bb+(size_t)blockIdx.x*H+c0),rb);
    float vb[4]={b4.x,b4.y,b4.z,b4.w};
    float v[4];
    #pragma unroll
    for(int j=0;j<4;j++){
      v[j]=gelu_f(acc[n8][j]+vb[j]+rb[j]);
    }
    *(uint2*)((char*)T+(u32)rl*256+(((u32)(2*c0))^rsw))=pk4(v);
  }
  f32x4 a2[8];
  #pragma unroll
  for(int n8=0;n8<8;n8++) a2[n8]=(f32x4){0.f,0.f,0.f,0.f};
  #pragma unroll
  for(int kc=0;kc<4;kc++){
    u32 cb=(u32)((kc*32+lk*8)*2);
    s16x8 bf=*(const s16x8*)((char*)T+(u32)rl*256+(cb^rsw));
    #pragma unroll
    for(int n8=0;n8<8;n8++){
      s16x8 af=*(const s16x8*)(W2p+((n8*4+kc)<<9)+lane*8);
      a2[n8]=__builtin_amdgcn_mfma_f32_16x16x32_bf16(af,bf,a2[n8],0,0,0);
    }
  }
  {
    float s=0.f,q=0.f;
    #pragma unroll
    for(int n8=0;n8<8;n8++){
      int c0=n8*16+lk*4;
      float4 b4=*(const float4*)(cb2+c0);
      float vb[4]={b4.x,b4.y,b4.z,b4.w};
      #pragma unroll
      for(int j=0;j<4;j++){
        float v=a2[n8][j]+vb[j];
        a2[n8][j]=v;
        s+=v; q+=v*v;
      }
    }
    s+=__shfl_xor(s,16); s+=__shfl_xor(s,32);
    q+=__shfl_xor(q,16); q+=__shfl_xor(q,32);
    float mu=s*(1.f/128.f);
    float rsig=rsqrtf(q*(1.f/128.f)-mu*mu+1e-5f);
    #pragma unroll
    for(int n8=0;n8<8;n8++){
      int c0=n8*16+lk*4;
      float4 g4=*(const float4*)(lng+c0);
      float4 e4=*(const float4*)(lnb+c0);
      float g[4]={g4.x,g4.y,g4.z,g4.w}, e[4]={e4.x,e4.y,e4.z,e4.w};
      float ov[4];
      #pragma unroll
      for(int j=0;j<4;j++) ov[j]=(a2[n8][j]-mu)*rsig*g[j]+e[j];
      *(uint2*)((char*)T+(u32)rl*256+(((u32)(2*c0))^rsw))=pk4(ov);
    }
  }
  pbuf[t]=0.f;
  if(t<2){
    int s=0;
    for(int j2=0;j2<32;j2++) s+=validv[row0+t*32+j2]?1:0;
    cntsh[t]=fmaxf((float)s,1.f);
  }
  __syncthreads();
  const uint4* hp=(const uint4*)(hres+(size_t)row0*H);
  float s0[8]={0,0,0,0,0,0,0,0}, s1[8]={0,0,0,0,0,0,0,0};
  #pragma unroll
  for(int p=0;p<4;p++){
    int i=t+p*256;
    u32 row=(u32)(i>>4), colb=(u32)((i&15)*16);
    int grow=row0+(int)row;
    uint4 v=*(const uint4*)((const char*)T+row*256+(colb^((row&7)<<4)));
    uint4 r=hp[i];
    float vv[8],rv[8];
    unp8(v,vv); unp8(r,rv);
    float vm=validv[grow]?1.f:0.f;
    #pragma unroll
    for(int j2=0;j2<8;j2++){
      float hh=(rv[j2]+vv[j2])*vm;
      if(p<2) s0[j2]+=hh; else s1[j2]+=hh;
    }
  }
  #pragma unroll
  for(int j2=0;j2<8;j2++){
    s0[j2]+=__shfl_xor(s0[j2],16); s0[j2]+=__shfl_xor(s0[j2],32);
    s1[j2]+=__shfl_xor(s1[j2],16); s1[j2]+=__shfl_xor(s1[j2],32);
  }
  if((lane&48)==0){
    int ch=(lane&15)*8;
    #pragma unroll
    for(int j2=0;j2<8;j2++){
      atomicAdd(&pbuf[ch+j2],s0[j2]);
      atomicAdd(&pbuf[128+ch+j2],s1[j2]);
    }
  }
  __syncthreads();
  if(t<128){
    float nodef=0.5f*(pbuf[t]/cntsh[0]+pbuf[128+t]/cntsh[1]);
    atomicAdd(&oacc[batch[blockIdx.x]*H+t],nodef);
  }
}

__global__ void k_out(const float* __restrict__ acc, const int* __restrict__ flag, void* __restrict__ out){
  int i=blockIdx.x*blockDim.x+threadIdx.x;
  if(i>=NGRAPH*H) return;
  if(*flag) ((__hip_bfloat16*)out)[i]=__float2bfloat16(acc[i]);
  else ((float*)out)[i]=acc[i];
}

extern "C" void kernel_launch(void* const* d_in, const int* in_sizes, int n_in,
                              void* d_out, int out_size, void* d_ws, size_t ws_size,
                              hipStream_t stream){
  (void)n_in; (void)out_size;
  int pofs[27]; pofs[0]=0;
  for(int i=0;i<26;i++) pofs[i+1]=pofs[i]+in_sizes[i];
  int ptot=pofs[26];

  char* wsb=(char*)d_ws;
  size_t off=0;
  auto alloc=[&](size_t bytes)->char*{ char* p=wsb+off; off+=(bytes+255)&~(size_t)255; return p; };
  int*   flag =(int*)  alloc(4);
  float* par  =(float*)alloc((size_t)ptot*4);
  u16*   h    =(u16*)  alloc((size_t)SKK*H*2);
  u16*   X    =(u16*)  alloc((size_t)SKK*H*2);
  u16*   wt   =(u16*)  alloc((size_t)28*HH*2);
  u16*   wt3  =(u16*)  alloc((size_t)HH*2);
  float* bias3=(float*)alloc(H*4);
  float* rf   =(float*)alloc((size_t)NN*H*4);
  u16*   bondb=(u16*)  alloc((size_t)16*H*2);
  u16*   hn   =(u16*)  alloc((size_t)NN*H*2);
  u16*   ag   =(u16*)  alloc((size_t)NN*H*2);
  u16*   bb   =(u16*)  alloc((size_t)NN*H*2);
  // ---- contiguous zero-init region ----
  int*   ecnt =(int*)  alloc(SS*4);
  int*   ecur =(int*)  alloc(SS*4);
  int*   gcnt =(int*)  alloc(NN*4);
  int*   gcur =(int*)  alloc(NN*4);
  float* stats=(float*)alloc(LNUM*512*4);
  float* oacc =(float*)alloc((size_t)NGRAPH*H*4);
  size_t zbytes=(size_t)SS*4+SS*4+NN*4+NN*4+LNUM*512*4+(size_t)NGRAPH*H*4;
  // ---- rest ----
  int* eoff  =(int*)alloc(SS*4);
  int* epack =(int*)alloc((size_t)EI*4);
  int* dstoff=(int*)alloc((size_t)SS*32*4);
  int* goff  =(int*)alloc(NN*4);
  int* gpack =(int*)alloc((size_t)EG*4);

  if(off>ws_size) return;

  const int* xids =(const int*)d_in[26];
  const int* iei  =(const int*)d_in[27];
  const int* iea  =(const int*)d_in[28];
  const int* gei  =(const int*)d_in[29];
  const int* gea  =(const int*)d_in[30];
  const int* nids =(const int*)d_in[31];
  const int* valid=(const int*)d_in[32];
  const int* batch=(const int*)d_in[33];

  const float* atom=par+pofs[0];
  const float* bond=par+pofs[1];
  const float* rw_w=par+pofs[2];
  const float* rw_b=par+pofs[3];
  const float* rwse=par+pofs[4];
  const float* leps=par+pofs[5];
  const float* lb1 =par+pofs[7];
  const float* lb2 =par+pofs[9];
  const float* lbng=par+pofs[10];
  const float* lbnb=par+pofs[11];
  const float* geps=par+pofs[12];
  const float* gb1 =par+pofs[14];
  const float* gb2 =par+pofs[16];
  const float* gbng=par+pofs[17];
  const float* gbnb=par+pofs[18];
  const float* cw1 =par+pofs[20];
  const float* cb1 =par+pofs[21];
  const float* cb2 =par+pofs[23];
  const float* lngp=par+pofs[24];
  const float* lnbp=par+pofs[25];

  k_sniff<<<1,256,0,stream>>>((const u16*)d_in[0], flag);
  CvtArgs ca;
  for(int i=0;i<26;i++){ ca.p[i]=d_in[i]; ca.start[i]=pofs[i]; }
  ca.start[26]=ptot;
  k_convert<<<1024,256,0,stream>>>(ca, flag, par);

  TransArgs ta;
  for(int l=0;l<LNUM;l++){
    ta.src[l*7+0]=pofs[6]+l*HH;
    ta.src[l*7+1]=pofs[8]+l*HH;
    ta.src[l*7+2]=pofs[13]+l*HH;
    ta.src[l*7+3]=pofs[15]+l*HH;
    ta.src[l*7+4]=pofs[19]+l*HH;
    ta.src[l*7+5]=pofs[20]+l*2*HH+HH;
    ta.src[l*7+6]=pofs[22]+l*HH;
  }
  k_trans<<<28,256,0,stream>>>(par, ta, wt);
  k_cvtbond<<<8,256,0,stream>>>(bond, bondb);

  (void)hipMemsetAsync(ecnt,0,zbytes,stream);

  k_hist<<<2048,256,0,stream>>>(iei+EI, EI, 5, ecnt);
  k_scan<<<1,1024,0,stream>>>(ecnt, eoff, SS);
  k_scatter_i<<<2048,256,0,stream>>>(iei, iea, eoff, ecur, epack);
  k_sortsub<<<SS,128,0,stream>>>(eoff, ecnt, epack, dstoff);
  k_hist<<<512,256,0,stream>>>(gei+EG, EG, 0, gcnt);
  k_scan<<<1,1024,0,stream>>>(gcnt, goff, NN);
  k_scatter_g<<<512,256,0,stream>>>(gei, gea, goff, gcur, gpack);

  k_rwse<<<NN,128,0,stream>>>(rwse, rw_w, rw_b, rf);

  for(int l=0;l<LNUM;l++){
    float* stl_l=stats+l*512;
    float* stg_l=stats+l*512+256;
    if(l==0){
      k_fused1<2><<<SS/2,256,0,stream>>>(h, bondb, eoff, ecnt, epack, dstoff, leps, l,
          wt+(size_t)(l*7+0)*HH, lb1+l*H, wt+(size_t)(l*7+1)*HH, lb2+l*H, X, stl_l,
          nullptr,nullptr,nullptr,nullptr,nullptr,nullptr,nullptr, valid, h,
          atom, rf, xids, nids, hn);
    } else {
      int pl=l-1;
      k_fused1<1><<<SS/2,256,0,stream>>>(h, bondb, eoff, ecnt, epack, dstoff, leps, l,
          wt+(size_t)(l*7+0)*HH, lb1+l*H, wt+(size_t)(l*7+1)*HH, lb2+l*H, X, stl_l,
          wt3, bias3, bb, wt+(size_t)(pl*7+6)*HH, cb2+pl*H,
          lngp+pl*H, lnbp+pl*H, valid, h,
          nullptr, nullptr, nullptr, nullptr, hn);
    }
    k_prepw3<<<128,128,0,stream>>>(cw1+(size_t)l*2*HH, cb1+l*H, stl_l, lbng+l*H, lbnb+l*H, wt3, bias3);
    k_node<<<NN/64,256,0,stream>>>(hn, bondb, goff, gcnt, gpack, geps, l,
        wt+(size_t)(l*7+2)*HH, gb1+l*H, wt+(size_t)(l*7+3)*HH, gb2+l*H, ag, stg_l);
    k_bcast<<<NN/64,256,0,stream>>>(hn, ag, stg_l, gbng+l*H, gbnb+l*H,
        wt+(size_t)(l*7+4)*HH, wt+(size_t)(l*7+5)*HH, bb);
  }
  {
    int l=LNUM-1;
    k_tailpool<<<SKK/64,256,0,stream>>>(X, wt3, bias3, bb,
        wt+(size_t)(l*7+6)*HH, cb2+l*H, lngp+l*H, lnbp+l*H, valid, h, batch, oacc);
  }
  k_out<<<(NGRAPH*H+255)/256,256,0,stream>>>(oacc, flag, d_out);
}